// Round 10
// baseline (1322.999 us; speedup 1.0000x reference)
//
#include <hip/hip_runtime.h>
#include <math.h>

#define DIM 512
#define NB 256
#define KMAX 16     // Taylor terms (powers A^1..A^16)
#define NBLK 512    // persistent grid: 2 blocks/CU guaranteed co-resident
#define MAGIC 0x13579BDF

using bf16x8 = __attribute__((ext_vector_type(8))) short;
using f32x4  = __attribute__((ext_vector_type(4))) float;
using float4v = __attribute__((ext_vector_type(4))) float;
using ushort4v = __attribute__((ext_vector_type(4))) unsigned short;

__device__ __forceinline__ unsigned short f2b(float f) {
    union { float f; unsigned int u; } v; v.f = f;
    unsigned int r = v.u + 0x7fffu + ((v.u >> 16) & 1u);
    return (unsigned short)(r >> 16);
}
__device__ __forceinline__ float b2f(unsigned short u) {
    union { unsigned int u; float f; } v; v.u = ((unsigned int)u) << 16;
    return v.f;
}
__device__ __forceinline__ ushort4v f2b4(float4v v) {
    ushort4v o;
    o.x = f2b(v.x); o.y = f2b(v.y); o.z = f2b(v.z); o.w = f2b(v.w);
    return o;
}

// ---------------------------------------------------------------------------
struct GemmDesc {
    const unsigned short* X;
    const unsigned short* W;
    const float* bias;
    float* Cf;
    unsigned short* Cb;
    unsigned short* Ct;
    int M, N, K, ldX, ldW, ldC, tr_row0, acc;
};

#define NSEG 13
struct PrepArgs {
    const float* sA[NSEG]; const float* sB[NSEG]; unsigned short* dst[NSEG];
    int n4[NSEG], dRL4[NSEG], sRLA4[NSEG], sRLB4[NSEG], half4[NSEG], offA[NSEG];
    const float* A; unsigned short* ATb;
    const float* aout_w; unsigned short* aout_wT;
    const float* proj_w; const float* proj_b; const float* aout_b; float* bprime;
};

struct MegaArgs {
    PrepArgs prep;
    GemmDesc g[18];
    // fused LN/GELU/delta
    const float* ln_pre; const float* ln_g; const float* ln_beta;
    const float* ln_w2; const float* ln_b2; float* ln_delta; float* ln_coeff;
    // pointwise
    const float* Tm; const float* coeff; const float* h_prev; const float* delta;
    const float* Bx; float* hssm; unsigned short* combb;
    const float* gates; const float* bih; const float* bhh; const float* cin;
    const float* decays; float* hout; float* cout;
    // attn
    const unsigned short* qb; const unsigned short* kvb;
    // final LN
    const float* fin_in; const float* fin_g; const float* fin_beta; float* fin_out;
    int* bar;
};

// ---------------------------------------------------------------------------
// device-wide barrier (poison-safe: bar[0]=ready flag, bar[1+k]=counter k)
// ---------------------------------------------------------------------------
__device__ __forceinline__ void devbar(int* bar, int k)
{
    __syncthreads();
    if (threadIdx.x == 0) {
        __threadfence();   // release this block's writes
        while (__hip_atomic_load(&bar[0], __ATOMIC_ACQUIRE, __HIP_MEMORY_SCOPE_AGENT) != MAGIC)
            __builtin_amdgcn_s_sleep(8);
        atomicAdd(&bar[1 + k], 1);
        while (__hip_atomic_load(&bar[1 + k], __ATOMIC_ACQUIRE, __HIP_MEMORY_SCOPE_AGENT) < NBLK)
            __builtin_amdgcn_s_sleep(8);
    }
    __syncthreads();
    __threadfence();       // acquire: invalidate L1 on every wave
}

__device__ __forceinline__ void block_reduce2(float& s, float& q, float* sb1, float* sb2)
{
    int tid = threadIdx.x;
    #pragma unroll
    for (int off = 32; off > 0; off >>= 1) {
        s += __shfl_down(s, off);
        q += __shfl_down(q, off);
    }
    if ((tid & 63) == 0) { sb1[tid >> 6] = s; sb2[tid >> 6] = q; }
    __syncthreads();
    s = sb1[0] + sb1[1] + sb1[2] + sb1[3];
    q = sb2[0] + sb2[1] + sb2[2] + sb2[3];
    __syncthreads();
}

// ---------------------------------------------------------------------------
// one 64x64 GEMM tile (identical math to round 9)
// ---------------------------------------------------------------------------
__device__ __forceinline__ void gemm_tile(const GemmDesc& de, int t,
    unsigned short lsA[2][4096], unsigned short lsB[2][4096])
{
    int tn = de.N >> 6;
    int m0 = (t / tn) << 6;
    int n0 = (t % tn) << 6;

    int tid = threadIdx.x;
    int w = tid >> 6;
    int l = tid & 63;
    int nkt = de.K >> 6;

    int srow = w * 16 + (l >> 2);
    int schk = l & 3;
    const unsigned short* gA = de.X + (size_t)(m0 + srow) * de.ldX + schk * 8;
    const unsigned short* gB = de.W + (size_t)(n0 + srow) * de.ldW + schk * 8;
    unsigned short* lA = &lsA[0][(w * 64 + l) * 8];
    unsigned short* lB = &lsB[0][(w * 64 + l) * 8];

#define STAGE(bufi, kt)                                                          \
    do {                                                                         \
        __builtin_amdgcn_global_load_lds(                                        \
            (const __attribute__((address_space(1))) unsigned int*)(gA + (size_t)(kt) * 64), \
            (__attribute__((address_space(3))) unsigned int*)(lA + (bufi) * 4096), 16, 0, 0); \
        __builtin_amdgcn_global_load_lds(                                        \
            (const __attribute__((address_space(1))) unsigned int*)(gA + (size_t)(kt) * 64 + 32), \
            (__attribute__((address_space(3))) unsigned int*)(lA + (bufi) * 4096 + 2048), 16, 0, 0); \
        __builtin_amdgcn_global_load_lds(                                        \
            (const __attribute__((address_space(1))) unsigned int*)(gB + (size_t)(kt) * 64), \
            (__attribute__((address_space(3))) unsigned int*)(lB + (bufi) * 4096), 16, 0, 0); \
        __builtin_amdgcn_global_load_lds(                                        \
            (const __attribute__((address_space(1))) unsigned int*)(gB + (size_t)(kt) * 64 + 32), \
            (__attribute__((address_space(3))) unsigned int*)(lB + (bufi) * 4096 + 2048), 16, 0, 0); \
    } while (0)

    int mbase = (w >> 1) * 32;
    int nbase = (w & 1) * 32;

    f32x4 acc[2][2];
    #pragma unroll
    for (int i = 0; i < 2; ++i)
        #pragma unroll
        for (int j = 0; j < 2; ++j)
            acc[i][j] = (f32x4){0.f, 0.f, 0.f, 0.f};

    int kg = l >> 4;
    int fr = l & 15;
    int aslot = (mbase * 4 + fr * 4 + kg) * 8;
    int bslot = (nbase * 4 + fr * 4 + kg) * 8;

    STAGE(0, 0);

    for (int kt = 0; kt < nkt; ++kt) {
        __syncthreads();
        if (kt + 1 < nkt) STAGE((kt + 1) & 1, kt + 1);

        const unsigned short* bufA = &lsA[kt & 1][0];
        const unsigned short* bufB = &lsB[kt & 1][0];
        #pragma unroll
        for (int h = 0; h < 2; ++h) {
            bf16x8 a0 = *(const bf16x8*)(bufA + h * 2048 + aslot);
            bf16x8 a1 = *(const bf16x8*)(bufA + h * 2048 + aslot + 512);
            bf16x8 b0 = *(const bf16x8*)(bufB + h * 2048 + bslot);
            bf16x8 b1 = *(const bf16x8*)(bufB + h * 2048 + bslot + 512);
            acc[0][0] = __builtin_amdgcn_mfma_f32_16x16x32_bf16(a0, b0, acc[0][0], 0, 0, 0);
            acc[0][1] = __builtin_amdgcn_mfma_f32_16x16x32_bf16(a0, b1, acc[0][1], 0, 0, 0);
            acc[1][0] = __builtin_amdgcn_mfma_f32_16x16x32_bf16(a1, b0, acc[1][0], 0, 0, 0);
            acc[1][1] = __builtin_amdgcn_mfma_f32_16x16x32_bf16(a1, b1, acc[1][1], 0, 0, 0);
        }
    }
    __syncthreads();   // all LDS reads done before next tile restages

    #pragma unroll
    for (int mi = 0; mi < 2; ++mi) {
        #pragma unroll
        for (int ni = 0; ni < 2; ++ni) {
            int col = n0 + nbase + ni * 16 + fr;
            float bv = de.bias ? de.bias[col] : 0.f;
            #pragma unroll
            for (int r = 0; r < 4; ++r) {
                int row = m0 + mbase + mi * 16 + (l >> 4) * 4 + r;
                float v = acc[mi][ni][r] + bv;
                if (de.Cf) {
                    if (de.acc) de.Cf[(size_t)row * de.ldC + col] += v;
                    else        de.Cf[(size_t)row * de.ldC + col] = v;
                } else {
                    de.Cb[(size_t)row * de.ldC + col] = f2b(v);
                }
                if (de.Ct && row >= de.tr_row0)
                    de.Ct[(size_t)col * 512 + (row - de.tr_row0)] = f2b(v);
            }
        }
    }
#undef STAGE
}

__device__ __forceinline__ int job_tiles(const GemmDesc& d) {
    return (d.M >> 6) * (d.N >> 6);
}

__device__ __forceinline__ void run_jobs(const MegaArgs& a, int j0, int nj,
    unsigned short lsA[2][4096], unsigned short lsB[2][4096])
{
    int cnt[5], tot = 0;
    for (int j = 0; j < nj; ++j) { cnt[j] = job_tiles(a.g[j0 + j]); tot += cnt[j]; }
    for (int t = blockIdx.x; t < tot; t += NBLK) {
        int tt = t, j = 0;
        while (tt >= cnt[j]) { tt -= cnt[j]; ++j; }
        gemm_tile(a.g[j0 + j], tt, lsA, lsB);
    }
}

// ---------------------------------------------------------------------------
__device__ __forceinline__ void lnd_row(const MegaArgs& a, int b, float* sb1, float* sb2)
{
    int tid = threadIdx.x;
    int i0 = tid, i1 = tid + 256;
    float x0 = a.ln_pre[(size_t)b * DIM + i0];
    float x1 = a.ln_pre[(size_t)b * DIM + i1];
    float s = x0 + x1, q = x0 * x0 + x1 * x1;
    block_reduce2(s, q, sb1, sb2);
    float mean = s * (1.f / DIM);
    float var  = q * (1.f / DIM) - mean * mean;
    float inv  = rsqrtf(var + 1e-5f);
    float y0 = (x0 - mean) * inv * a.ln_g[i0] + a.ln_beta[i0];
    float y1 = (x1 - mean) * inv * a.ln_g[i1] + a.ln_beta[i1];
    float h0 = 0.5f * y0 * (1.f + erff(y0 * 0.70710678118654752f));
    float h1 = 0.5f * y1 * (1.f + erff(y1 * 0.70710678118654752f));
    float p = h0 * a.ln_w2[i0] + h1 * a.ln_w2[i1];
    float dummy = 0.f;
    block_reduce2(p, dummy, sb1, sb2);
    if (tid == 0) {
        float z = p + a.ln_b2[0];
        float d = (z > 20.f) ? z : log1pf(expf(z));
        a.ln_delta[b] = d;
        float c = 1.f;
        a.ln_coeff[b] = 1.f;
        for (int k = 1; k <= KMAX; ++k) { c *= d / (float)k; a.ln_coeff[k * 256 + b] = c; }
    }
}

__device__ __forceinline__ void fin_ln_row(const MegaArgs& a, int b, float* sb1, float* sb2)
{
    int tid = threadIdx.x;
    int i0 = tid, i1 = tid + 256;
    float x0 = a.fin_in[(size_t)b * DIM + i0];
    float x1 = a.fin_in[(size_t)b * DIM + i1];
    float s = x0 + x1, q = x0 * x0 + x1 * x1;
    block_reduce2(s, q, sb1, sb2);
    float mean = s * (1.f / DIM);
    float var  = q * (1.f / DIM) - mean * mean;
    float inv  = rsqrtf(var + 1e-5f);
    a.fin_out[(size_t)b * DIM + i0] = (x0 - mean) * inv * a.fin_g[i0] + a.fin_beta[i0];
    a.fin_out[(size_t)b * DIM + i1] = (x1 - mean) * inv * a.fin_g[i1] + a.fin_beta[i1];
}

// ---------------------------------------------------------------------------
__global__ __launch_bounds__(256, 2) void mega(MegaArgs a)
{
    __shared__ unsigned short lsA[2][4096];
    __shared__ unsigned short lsB[2][4096];
    __shared__ float tile[32][33];
    __shared__ float sb1[4], sb2[4];

    int bid = blockIdx.x, tid = threadIdx.x;
    int* bar = a.bar;

    // barrier init (poison-safe)
    if (bid == 0) {
        if (tid < 12) bar[1 + tid] = 0;
        __syncthreads();
        if (tid == 0) {
            __threadfence();
            __hip_atomic_store(&bar[0], MAGIC, __ATOMIC_RELEASE, __HIP_MEMORY_SCOPE_AGENT);
        }
    }

    // ---- S0: prep (converts + transposes + bprime) ----
    {
        const int gstride = NBLK * 256;
        int g0 = bid * 256 + tid;
        for (int seg = 0; seg < NSEG; ++seg) {
            int n4 = a.prep.n4[seg];
            const float* sA = a.prep.sA[seg];
            const float* sB = a.prep.sB[seg];
            unsigned short* d = a.prep.dst[seg];
            int dRL4 = a.prep.dRL4[seg], sRLA4 = a.prep.sRLA4[seg], sRLB4 = a.prep.sRLB4[seg];
            int half4 = a.prep.half4[seg], offA = a.prep.offA[seg];
            for (int i = g0; i < n4; i += gstride) {
                int r = i / dRL4, c = i - r * dRL4;
                const float* src = (c < half4)
                    ? sA + ((size_t)r * sRLA4 + offA + c) * 4
                    : sB + ((size_t)r * sRLB4 + (c - half4)) * 4;
                float4v v = *(const float4v*)src;
                *(ushort4v*)(d + (size_t)i * 4) = f2b4(v);
            }
        }
        // transposes: 512 tiles (256 for A^T, 256 for aout_w^T)
        for (int t = bid; t < 512; t += NBLK) {
            const float* src = (t < 256) ? a.prep.A : a.prep.aout_w;
            unsigned short* dst = (t < 256) ? a.prep.ATb : a.prep.aout_wT;
            int tt = t & 255;
            int bx = tt & 15, by = tt >> 4;
            int tx = tid & 31, ty = tid >> 5;
            #pragma unroll
            for (int i = 0; i < 32; i += 8)
                tile[ty + i][tx] = src[(size_t)(by * 32 + ty + i) * 512 + bx * 32 + tx];
            __syncthreads();
            #pragma unroll
            for (int i = 0; i < 32; i += 8)
                dst[(size_t)(bx * 32 + ty + i) * 512 + by * 32 + tx] = f2b(tile[tx][ty + i]);
            __syncthreads();
        }
        // bprime: one wave per row
        int gw = bid * 4 + (tid >> 6);
        int lane = tid & 63;
        for (int i = gw; i < 512; i += NBLK * 4) {
            float acc = 0.f;
            #pragma unroll
            for (int n = 0; n < 512; n += 64)
                acc += a.prep.proj_w[(size_t)i * 2560 + 512 + n + lane] * a.prep.aout_b[n + lane];
            #pragma unroll
            for (int off = 32; off > 0; off >>= 1) acc += __shfl_down(acc, off);
            if (lane == 0) a.prep.bprime[i] = a.prep.proj_b[i] + acc;
        }
    }
    devbar(bar, 0);

    // ---- S1: dense1, Bx, M2, A^2(+Q2)  [g0..g3] ----
    run_jobs(a, 0, 4, lsA, lsB);
    devbar(bar, 1);

    // ---- S2: LN/GELU/delta (tiles 0..255) + G2 [A^3,A^4]+Q4 (g4) ----
    for (int t = bid; t < 256 + 128; t += NBLK) {
        if (t < 256) lnd_row(a, t, sb1, sb2);
        else         gemm_tile(a.g[4], t - 256, lsA, lsB);
    }
    devbar(bar, 2);

    // ---- S3: G3 [A^5..A^8]+Q8 (g5) ----
    run_jobs(a, 5, 1, lsA, lsB);
    devbar(bar, 3);

    // ---- S4: G4 [A^9..A^16] + Taylor1 + LSTM x3 (g6..g10) ----
    run_jobs(a, 6, 5, lsA, lsB);
    devbar(bar, 4);

    // ---- S5: Taylor2 (g11) ----
    run_jobs(a, 11, 1, lsA, lsB);
    devbar(bar, 5);

    // ---- S6: pointwise (taylor accum + lstm cell) ----
    for (int idx4 = bid * 256 + tid; idx4 < 131072; idx4 += NBLK * 256) {
        int base = idx4 * 4;
        if (base < 131072) {
            int b = base >> 9, i = base & 511;
            const float* Tr = a.Tm + (size_t)b * (KMAX * DIM) + i;
            float4v acc4 = *(const float4v*)(a.h_prev + base);
            #pragma unroll
            for (int k = 1; k <= KMAX; ++k) {
                float c = a.coeff[k * 256 + b];
                float4v t = *(const float4v*)(Tr + (size_t)(k - 1) * DIM);
                acc4.x += c * t.x; acc4.y += c * t.y; acc4.z += c * t.z; acc4.w += c * t.w;
            }
            float dl = a.delta[b];
            float4v bx = *(const float4v*)(a.Bx + base);
            acc4.x += dl * bx.x; acc4.y += dl * bx.y; acc4.z += dl * bx.z; acc4.w += dl * bx.w;
            *(float4v*)(a.hssm + base) = acc4;
            *(ushort4v*)(a.combb + (size_t)b * 2560 + i) = f2b4(acc4);
        } else {
            int i2 = base - 131072;
            int s = i2 / (NB * DIM);
            int r = i2 - s * (NB * DIM);
            int b = r >> 9, d = r & 511;
            const float* gr = a.gates + (size_t)s * 524288 + (size_t)b * 2048 + d;
            const float* bi = a.bih + s * 2048 + d;
            const float* bh = a.bhh + s * 2048 + d;
            float4v gi = *(const float4v*)(gr);
            float4v gf = *(const float4v*)(gr + 512);
            float4v gg = *(const float4v*)(gr + 1024);
            float4v go = *(const float4v*)(gr + 1536);
            float4v bi0 = *(const float4v*)(bi),        bh0 = *(const float4v*)(bh);
            float4v bi1 = *(const float4v*)(bi + 512),  bh1 = *(const float4v*)(bh + 512);
            float4v bi2 = *(const float4v*)(bi + 1024), bh2 = *(const float4v*)(bh + 1024);
            float4v bi3 = *(const float4v*)(bi + 1536), bh3 = *(const float4v*)(bh + 1536);
            float4v c = *(const float4v*)(a.cin + i2);
            float dec = a.decays[s];
            float4v hn, cn;
            #pragma unroll
            for (int j = 0; j < 4; ++j) {
                float vgi = ((const float*)&gi)[j] + ((const float*)&bi0)[j] + ((const float*)&bh0)[j];
                float vgf = ((const float*)&gf)[j] + ((const float*)&bi1)[j] + ((const float*)&bh1)[j];
                float vgg = ((const float*)&gg)[j] + ((const float*)&bi2)[j] + ((const float*)&bh2)[j];
                float vgo = ((const float*)&go)[j] + ((const float*)&bi3)[j] + ((const float*)&bh3)[j];
                float ig = 1.f / (1.f + expf(-vgi));
                float fg = 1.f / (1.f + expf(-vgf));
                float g_ = tanhf(vgg);
                float og = 1.f / (1.f + expf(-vgo));
                float cc = ((const float*)&c)[j];
                float craw = fg * cc + ig * g_;
                ((float*)&hn)[j] = og * tanhf(craw);
                ((float*)&cn)[j] = dec * cc + (1.f - dec) * craw;
            }
            *(float4v*)(a.hout + i2) = hn;
            *(float4v*)(a.cout + i2) = cn;
            *(ushort4v*)(a.combb + (size_t)b * 2560 + 512 + s * 512 + d) = f2b4(hn);
        }
    }
    devbar(bar, 6);

    // ---- S7: q + kv x3 + projA (g12..g16) ----
    run_jobs(a, 12, 5, lsA, lsB);
    devbar(bar, 7);

    // ---- S8: attention (256 rows; threads 0..127 active) ----
    for (int b = bid; b < 256; b += NBLK) {
        if (tid < 128) {
            int h = tid >> 4, sub = (tid & 15) * 4;
            int col = h * 64 + sub;
            ushort4v q4 = *(const ushort4v*)(a.qb + (size_t)b * 512 + col);
            float qf[4] = { b2f(q4.x), b2f(q4.y), b2f(q4.z), b2f(q4.w) };
            float p[3];
            ushort4v k4[3], v4[3];
            #pragma unroll
            for (int s = 0; s < 3; ++s) {
                k4[s] = *(const ushort4v*)(a.kvb + (size_t)s * 262144 + (size_t)b * 1024 + col);
                v4[s] = *(const ushort4v*)(a.kvb + (size_t)s * 262144 + (size_t)b * 1024 + 512 + col);
                p[s] = qf[0] * b2f(k4[s].x) + qf[1] * b2f(k4[s].y)
                     + qf[2] * b2f(k4[s].z) + qf[3] * b2f(k4[s].w);
            }
            #pragma unroll
            for (int off = 1; off < 16; off <<= 1) {
                p[0] += __shfl_xor(p[0], off);
                p[1] += __shfl_xor(p[1], off);
                p[2] += __shfl_xor(p[2], off);
            }
            const float scale = 0.125f;
            float p0 = p[0] * scale, p1 = p[1] * scale, p2 = p[2] * scale;
            float m = fmaxf(p0, fmaxf(p1, p2));
            float w0 = expf(p0 - m), w1 = expf(p1 - m), w2 = expf(p2 - m);
            float invs = 1.f / (w0 + w1 + w2);
            float4v ctx;
            ((float*)&ctx)[0] = (w0 * b2f(v4[0].x) + w1 * b2f(v4[1].x) + w2 * b2f(v4[2].x)) * invs;
            ((float*)&ctx)[1] = (w0 * b2f(v4[0].y) + w1 * b2f(v4[1].y) + w2 * b2f(v4[2].y)) * invs;
            ((float*)&ctx)[2] = (w0 * b2f(v4[0].z) + w1 * b2f(v4[1].z) + w2 * b2f(v4[2].z)) * invs;
            ((float*)&ctx)[3] = (w0 * b2f(v4[0].w) + w1 * b2f(v4[1].w) + w2 * b2f(v4[2].w)) * invs;
            *(ushort4v*)(a.combb + (size_t)b * 2560 + 2048 + col) = f2b4(ctx);
        }
    }
    devbar(bar, 8);

    // ---- S9: projB (acc into projout) (g17) ----
    run_jobs(a, 17, 1, lsA, lsB);
    devbar(bar, 9);

    // ---- S10: final LN ----
    for (int b = bid; b < 256; b += NBLK)
        fin_ln_row(a, b, sb1, sb2);
}

// ---------------------------------------------------------------------------
extern "C" void kernel_launch(void* const* d_in, const int* in_sizes, int n_in,
                              void* d_out, int out_size, void* d_ws, size_t ws_size,
                              hipStream_t stream)
{
    const float* x        = (const float*)d_in[0];
    const float* h_prev   = (const float*)d_in[1];
    const float* lstm_h   = (const float*)d_in[2];
    const float* lstm_c   = (const float*)d_in[3];
    const float* A        = (const float*)d_in[4];
    const float* Bm       = (const float*)d_in[5];
    const float* dn_w1    = (const float*)d_in[6];
    const float* dn_b1    = (const float*)d_in[7];
    const float* dn_g     = (const float*)d_in[8];
    const float* dn_beta  = (const float*)d_in[9];
    const float* dn_w2    = (const float*)d_in[10];
    const float* dn_b2    = (const float*)d_in[11];
    const float* wih      = (const float*)d_in[12];
    const float* whh      = (const float*)d_in[13];
    const float* bih      = (const float*)d_in[14];
    const float* bhh      = (const float*)d_in[15];
    const float* decays   = (const float*)d_in[16];
    const float* ain_w    = (const float*)d_in[17];
    const float* ain_b    = (const float*)d_in[18];
    const float* aout_w   = (const float*)d_in[19];
    const float* aout_b   = (const float*)d_in[20];
    const float* proj_w   = (const float*)d_in[21];
    const float* proj_b   = (const float*)d_in[22];
    const float* proj_g   = (const float*)d_in[23];
    const float* proj_bt  = (const float*)d_in[24];

    float* out  = (float*)d_out;
    float* hssm = out + 131072;
    float* hnew = out + 262144;
    float* cnew = out + 655360;

    // ---- workspace (bf16 section) ----
    unsigned short* us = (unsigned short*)d_ws;
    unsigned short* hpb     = us;                  // 131072
    unsigned short* ATb     = us + 131072;         // 262144
    unsigned short* dn_w1b  = us + 393216;         // 262144
    unsigned short* Bmb     = us + 655360;         // 262144
    unsigned short* ain_wb  = us + 917504;         // 786432
    unsigned short* proj_wb = us + 1703936;        // 1048576 (512 x 2048 packed [P0|P1])
    unsigned short* P2b     = us + 3014656;        // 262144
    unsigned short* aout_wT = us + 3276800;        // 262144
    unsigned short* Pw      = us + 3538944;        // 16*262144 [A^1..A^16]
    unsigned short* Qa      = us + 7733248;        // 262144
    unsigned short* Qb      = us + 7995392;        // 262144
    unsigned short* Wcat    = us + 8257536;        // 6291456
    unsigned short* Xcat    = us + 14548992;       // 786432
    unsigned short* combb   = us + 15335424;       // 655360 (256 x 2560) [hssm|hnew*3|ctx]
    unsigned short* qb      = us + 15990784;       // 131072
    unsigned short* kvb     = us + 16121856;       // 786432
    unsigned short* M2b     = us + 16908288;       // 262144 (512 x 512)
    // ---- fp32 section ----
    float* fbase  = (float*)(us + 17170432);
    float* pre1   = fbase;                         // 131072 (reused as projout)
    float* delta  = fbase + 131072;                // 256
    float* coeff  = fbase + 131328;                // 17*256
    float* Bx     = fbase + 135680;                // 131072
    float* bprime = fbase + 266752;                // 512
    float* Tm     = fbase + 267264;                // 256*8192
    float* gates  = fbase + 2364416;               // 1572864
    int*   bar    = (int*)(fbase + 3937280);       // 16 ints
    float* projout = pre1;

    MegaArgs ma;

    // ---- prep args (13 segments) ----
    int sidx = 0;
    auto LIN = [&](const float* s, unsigned short* d, int n4) {
        ma.prep.sA[sidx]=s; ma.prep.sB[sidx]=s; ma.prep.dst[sidx]=d; ma.prep.n4[sidx]=n4;
        ma.prep.dRL4[sidx]=n4; ma.prep.sRLA4[sidx]=0; ma.prep.sRLB4[sidx]=0;
        ma.prep.half4[sidx]=n4; ma.prep.offA[sidx]=0; ++sidx;
    };
    LIN(h_prev, hpb,     32768);
    LIN(A,      Pw,      65536);
    LIN(dn_w1,  dn_w1b,  65536);
    LIN(Bm,     Bmb,     65536);
    LIN(ain_w,  ain_wb,  196608);
    ma.prep.sA[sidx]=proj_w; ma.prep.sB[sidx]=proj_w + 1024; ma.prep.dst[sidx]=proj_wb; ma.prep.n4[sidx]=262144;
    ma.prep.dRL4[sidx]=512; ma.prep.sRLA4[sidx]=640; ma.prep.sRLB4[sidx]=640; ma.prep.half4[sidx]=128; ma.prep.offA[sidx]=0; ++sidx;
    ma.prep.sA[sidx]=proj_w; ma.prep.sB[sidx]=proj_w; ma.prep.dst[sidx]=P2b; ma.prep.n4[sidx]=65536;
    ma.prep.dRL4[sidx]=128; ma.prep.sRLA4[sidx]=640; ma.prep.sRLB4[sidx]=640; ma.prep.half4[sidx]=128; ma.prep.offA[sidx]=128; ++sidx;
    for (int s = 0; s < 3; ++s) {
        ma.prep.sA[sidx]=wih + (size_t)s*1048576; ma.prep.sB[sidx]=whh + (size_t)s*1048576;
        ma.prep.dst[sidx]=Wcat + (size_t)s*2097152; ma.prep.n4[sidx]=524288;
        ma.prep.dRL4[sidx]=256; ma.prep.sRLA4[sidx]=128; ma.prep.sRLB4[sidx]=128; ma.prep.half4[sidx]=128; ma.prep.offA[sidx]=0; ++sidx;
    }
    for (int s = 0; s < 3; ++s) {
        ma.prep.sA[sidx]=x; ma.prep.sB[sidx]=lstm_h + (size_t)s*131072;
        ma.prep.dst[sidx]=Xcat + (size_t)s*262144; ma.prep.n4[sidx]=65536;
        ma.prep.dRL4[sidx]=256; ma.prep.sRLA4[sidx]=128; ma.prep.sRLB4[sidx]=128; ma.prep.half4[sidx]=128; ma.prep.offA[sidx]=0; ++sidx;
    }
    ma.prep.A = A; ma.prep.ATb = ATb; ma.prep.aout_w = aout_w; ma.prep.aout_wT = aout_wT;
    ma.prep.proj_w = proj_w; ma.prep.proj_b = proj_b; ma.prep.aout_b = aout_b; ma.prep.bprime = bprime;

    // ---- GEMM descriptors (identical to round 9) ----
    ma.g[0]  = { Xcat, dn_w1b, dn_b1, pre1, nullptr, nullptr, 256, 512, 512, 1024, 512, 512, 0, 0 };
    ma.g[1]  = { Xcat, Bmb,    nullptr, Bx,  nullptr, nullptr, 256, 512, 512, 1024, 512, 512, 0, 0 };
    ma.g[2]  = { P2b,  aout_wT, nullptr, nullptr, M2b, nullptr, 512, 512, 512, 512, 512, 512, 0, 0 };
    ma.g[3]  = { Pw, ATb, nullptr, nullptr, Pw + 1*262144, Qa, 512, 512, 512, 512, 512, 512, 0, 0 };
    ma.g[4]  = { Pw, Qa, nullptr, nullptr, Pw + 2*262144, Qb, 1024, 512, 512, 512, 512, 512, 512, 0 };
    ma.g[5]  = { Pw, Qb, nullptr, nullptr, Pw + 4*262144, Qa, 2048, 512, 512, 512, 512, 512, 1536, 0 };
    ma.g[6]  = { Pw, Qa, nullptr, nullptr, Pw + 8*262144, nullptr, 4096, 512, 512, 512, 512, 512, 0, 0 };
    ma.g[7]  = { hpb, Pw, nullptr, Tm, nullptr, nullptr, 256, 4096, 512, 512, 512, 8192, 0, 0 };
    for (int s = 0; s < 3; ++s)
        ma.g[8 + s] = { Xcat + (size_t)s * 262144, Wcat + (size_t)s * 2097152, nullptr,
                        gates + (size_t)s * 524288, nullptr, nullptr, 256, 2048, 1024, 1024, 1024, 2048, 0, 0 };
    ma.g[11] = { hpb, Pw + 8*262144, nullptr, Tm + 4096, nullptr, nullptr, 256, 4096, 512, 512, 512, 8192, 0, 0 };
    ma.g[12] = { combb, ain_wb, ain_b, nullptr, qb, nullptr, 256, 512, 512, 2560, 512, 512, 0, 0 };
    for (int s = 0; s < 3; ++s)
        ma.g[13 + s] = { combb + 512 + (size_t)s * 512, ain_wb + 262144, ain_b + 512,
                         nullptr, kvb + (size_t)s * 262144, nullptr, 256, 1024, 512, 2560, 512, 1024, 0, 0 };
    ma.g[16] = { combb, proj_wb, bprime, projout, nullptr, nullptr, 256, 512, 2048, 2560, 2048, 512, 0, 0 };
    ma.g[17] = { combb + 2048, M2b, nullptr, projout, nullptr, nullptr, 256, 512, 512, 2560, 512, 512, 0, 1 };

    // ---- stage extras ----
    ma.ln_pre = pre1; ma.ln_g = dn_g; ma.ln_beta = dn_beta;
    ma.ln_w2 = dn_w2; ma.ln_b2 = dn_b2; ma.ln_delta = delta; ma.ln_coeff = coeff;
    ma.Tm = Tm; ma.coeff = coeff; ma.h_prev = h_prev; ma.delta = delta; ma.Bx = Bx;
    ma.hssm = hssm; ma.combb = combb;
    ma.gates = gates; ma.bih = bih; ma.bhh = bhh; ma.cin = lstm_c; ma.decays = decays;
    ma.hout = hnew; ma.cout = cnew;
    ma.qb = qb; ma.kvb = kvb;
    ma.fin_in = projout; ma.fin_g = proj_g; ma.fin_beta = proj_bt; ma.fin_out = out;
    ma.bar = bar;

    mega<<<NBLK, 256, 0, stream>>>(ma);
}

// Round 11
// 245.789 us; speedup vs baseline: 5.3827x; 5.3827x over previous
//
#include <hip/hip_runtime.h>
#include <math.h>

#define DIM 512
#define NB 256
#define KMAX 12   // Taylor terms (powers A^1..A^12)

using bf16x8 = __attribute__((ext_vector_type(8))) short;
using f32x4  = __attribute__((ext_vector_type(4))) float;
using float4v = __attribute__((ext_vector_type(4))) float;
using ushort4v = __attribute__((ext_vector_type(4))) unsigned short;

__device__ __forceinline__ unsigned short f2b(float f) {
    union { float f; unsigned int u; } v; v.f = f;
    unsigned int r = v.u + 0x7fffu + ((v.u >> 16) & 1u);
    return (unsigned short)(r >> 16);
}
__device__ __forceinline__ float b2f(unsigned short u) {
    union { unsigned int u; float f; } v; v.u = ((unsigned int)u) << 16;
    return v.f;
}
__device__ __forceinline__ ushort4v f2b4(float4v v) {
    ushort4v o;
    o.x = f2b(v.x); o.y = f2b(v.y); o.z = f2b(v.z); o.w = f2b(v.w);
    return o;
}

__device__ __forceinline__ void block_reduce2(float& s, float& q, float* sb1, float* sb2)
{
    int tid = threadIdx.x;
    #pragma unroll
    for (int off = 32; off > 0; off >>= 1) {
        s += __shfl_down(s, off);
        q += __shfl_down(q, off);
    }
    if ((tid & 63) == 0) { sb1[tid >> 6] = s; sb2[tid >> 6] = q; }
    __syncthreads();
    s = sb1[0] + sb1[1] + sb1[2] + sb1[3];
    q = sb2[0] + sb2[1] + sb2[2] + sb2[3];
    __syncthreads();
}

// ---------------------------------------------------------------------------
// Batched bf16 MFMA GEMM (round-9 proven core).  C[m,n]=sum_k X[m,k]W[n,k]+b.
// acc=1: Cf += .  Ct: transposed bf16 dual-write (rows>=tr_row0).
// lp.lnd_y == blockIdx.y -> fused LN/GELU/delta branch.
// ---------------------------------------------------------------------------
struct GemmDesc {
    const unsigned short* X;
    const unsigned short* W;
    const float* bias;
    float* Cf;
    unsigned short* Cb;
    unsigned short* Ct;
    int M, N, K, ldX, ldW, ldC, tr_row0, acc;
};
struct GemmArgs { GemmDesc d[6]; };
struct LnParams {
    const float* pre; const float* g; const float* beta;
    const float* w2; const float* b2; float* delta; float* coeff;
    int lnd_y;
};

__global__ __launch_bounds__(256) void gemm_mfma(GemmArgs args, LnParams lp)
{
    __shared__ unsigned short lsA[2][4096];
    __shared__ unsigned short lsB[2][4096];
    __shared__ float sb1[4], sb2[4];

    if ((int)blockIdx.y == lp.lnd_y) {
        int b = blockIdx.x, tid = threadIdx.x;
        int i0 = tid, i1 = tid + 256;
        float x0 = lp.pre[(size_t)b * DIM + i0];
        float x1 = lp.pre[(size_t)b * DIM + i1];
        float s = x0 + x1, q = x0 * x0 + x1 * x1;
        block_reduce2(s, q, sb1, sb2);
        float mean = s * (1.f / DIM);
        float var  = q * (1.f / DIM) - mean * mean;
        float inv  = rsqrtf(var + 1e-5f);
        float y0 = (x0 - mean) * inv * lp.g[i0] + lp.beta[i0];
        float y1 = (x1 - mean) * inv * lp.g[i1] + lp.beta[i1];
        float h0 = 0.5f * y0 * (1.f + erff(y0 * 0.70710678118654752f));
        float h1 = 0.5f * y1 * (1.f + erff(y1 * 0.70710678118654752f));
        float p = h0 * lp.w2[i0] + h1 * lp.w2[i1];
        float dummy = 0.f;
        block_reduce2(p, dummy, sb1, sb2);
        if (tid == 0) {
            float z = p + lp.b2[0];
            float d = (z > 20.f) ? z : log1pf(expf(z));
            lp.delta[b] = d;
            float c = 1.f;
            lp.coeff[b] = 1.f;
            for (int k = 1; k <= KMAX; ++k) { c *= d / (float)k; lp.coeff[k * 256 + b] = c; }
        }
        return;
    }

    GemmDesc de = args.d[blockIdx.y];
    int tn = de.N >> 6;
    int tiles = (de.M >> 6) * tn;
    int t = blockIdx.x;
    if (t >= tiles) return;
    int m0 = (t / tn) << 6;
    int n0 = (t % tn) << 6;

    int tid = threadIdx.x;
    int w = tid >> 6;
    int l = tid & 63;
    int nkt = de.K >> 6;

    int srow = w * 16 + (l >> 2);
    int schk = l & 3;
    const unsigned short* gA = de.X + (size_t)(m0 + srow) * de.ldX + schk * 8;
    const unsigned short* gB = de.W + (size_t)(n0 + srow) * de.ldW + schk * 8;
    unsigned short* lA = &lsA[0][(w * 64 + l) * 8];
    unsigned short* lB = &lsB[0][(w * 64 + l) * 8];

#define STAGE(bufi, kt)                                                          \
    do {                                                                         \
        __builtin_amdgcn_global_load_lds(                                        \
            (const __attribute__((address_space(1))) unsigned int*)(gA + (size_t)(kt) * 64), \
            (__attribute__((address_space(3))) unsigned int*)(lA + (bufi) * 4096), 16, 0, 0); \
        __builtin_amdgcn_global_load_lds(                                        \
            (const __attribute__((address_space(1))) unsigned int*)(gA + (size_t)(kt) * 64 + 32), \
            (__attribute__((address_space(3))) unsigned int*)(lA + (bufi) * 4096 + 2048), 16, 0, 0); \
        __builtin_amdgcn_global_load_lds(                                        \
            (const __attribute__((address_space(1))) unsigned int*)(gB + (size_t)(kt) * 64), \
            (__attribute__((address_space(3))) unsigned int*)(lB + (bufi) * 4096), 16, 0, 0); \
        __builtin_amdgcn_global_load_lds(                                        \
            (const __attribute__((address_space(1))) unsigned int*)(gB + (size_t)(kt) * 64 + 32), \
            (__attribute__((address_space(3))) unsigned int*)(lB + (bufi) * 4096 + 2048), 16, 0, 0); \
    } while (0)

    int mbase = (w >> 1) * 32;
    int nbase = (w & 1) * 32;

    f32x4 acc[2][2];
    #pragma unroll
    for (int i = 0; i < 2; ++i)
        #pragma unroll
        for (int j = 0; j < 2; ++j)
            acc[i][j] = (f32x4){0.f, 0.f, 0.f, 0.f};

    int kg = l >> 4;
    int fr = l & 15;
    int aslot = (mbase * 4 + fr * 4 + kg) * 8;
    int bslot = (nbase * 4 + fr * 4 + kg) * 8;

    STAGE(0, 0);

    for (int kt = 0; kt < nkt; ++kt) {
        __syncthreads();
        if (kt + 1 < nkt) STAGE((kt + 1) & 1, kt + 1);

        const unsigned short* bufA = &lsA[kt & 1][0];
        const unsigned short* bufB = &lsB[kt & 1][0];
        #pragma unroll
        for (int h = 0; h < 2; ++h) {
            bf16x8 a0 = *(const bf16x8*)(bufA + h * 2048 + aslot);
            bf16x8 a1 = *(const bf16x8*)(bufA + h * 2048 + aslot + 512);
            bf16x8 b0 = *(const bf16x8*)(bufB + h * 2048 + bslot);
            bf16x8 b1 = *(const bf16x8*)(bufB + h * 2048 + bslot + 512);
            acc[0][0] = __builtin_amdgcn_mfma_f32_16x16x32_bf16(a0, b0, acc[0][0], 0, 0, 0);
            acc[0][1] = __builtin_amdgcn_mfma_f32_16x16x32_bf16(a0, b1, acc[0][1], 0, 0, 0);
            acc[1][0] = __builtin_amdgcn_mfma_f32_16x16x32_bf16(a1, b0, acc[1][0], 0, 0, 0);
            acc[1][1] = __builtin_amdgcn_mfma_f32_16x16x32_bf16(a1, b1, acc[1][1], 0, 0, 0);
        }
    }

    #pragma unroll
    for (int mi = 0; mi < 2; ++mi) {
        #pragma unroll
        for (int ni = 0; ni < 2; ++ni) {
            int col = n0 + nbase + ni * 16 + fr;
            float bv = de.bias ? de.bias[col] : 0.f;
            #pragma unroll
            for (int r = 0; r < 4; ++r) {
                int row = m0 + mbase + mi * 16 + (l >> 4) * 4 + r;
                float v = acc[mi][ni][r] + bv;
                if (de.Cf) {
                    if (de.acc) de.Cf[(size_t)row * de.ldC + col] += v;
                    else        de.Cf[(size_t)row * de.ldC + col] = v;
                } else {
                    de.Cb[(size_t)row * de.ldC + col] = f2b(v);
                }
                if (de.Ct && row >= de.tr_row0)
                    de.Ct[(size_t)col * 512 + (row - de.tr_row0)] = f2b(v);
            }
        }
    }
#undef STAGE
}

// ---------------------------------------------------------------------------
// Unified prep: 14 convert segments + A^T transpose.  Grid 2304 x 256.
// Segment model (f4 units): r=i/dRL4, c=i%dRL4;
//   src = (c<half4) ? sA + (r*sRLA4+offA+c)*4 : sB + (r*sRLB4+c-half4)*4
// ---------------------------------------------------------------------------
#define NSEG 14
struct PrepArgs {
    const float* sA[NSEG]; const float* sB[NSEG]; unsigned short* dst[NSEG];
    int n4[NSEG], dRL4[NSEG], sRLA4[NSEG], sRLB4[NSEG], half4[NSEG], offA[NSEG];
    const float* A; unsigned short* ATb;
};
__global__ __launch_bounds__(256) void prep_kernel(PrepArgs a)
{
    __shared__ float tile[32][33];
    int bid = blockIdx.x, tid = threadIdx.x;
    if (bid < 2048) {
        const int gstride = 2048 * 256;
        int g0 = bid * 256 + tid;
        for (int seg = 0; seg < NSEG; ++seg) {
            int n4 = a.n4[seg];
            const float* sA = a.sA[seg];
            const float* sB = a.sB[seg];
            unsigned short* d = a.dst[seg];
            int dRL4 = a.dRL4[seg], sRLA4 = a.sRLA4[seg], sRLB4 = a.sRLB4[seg];
            int half4 = a.half4[seg], offA = a.offA[seg];
            for (int i = g0; i < n4; i += gstride) {
                int r = i / dRL4, c = i - r * dRL4;
                const float* src = (c < half4)
                    ? sA + ((size_t)r * sRLA4 + offA + c) * 4
                    : sB + ((size_t)r * sRLB4 + (c - half4)) * 4;
                float4v v = *(const float4v*)src;
                *(ushort4v*)(d + (size_t)i * 4) = f2b4(v);
            }
        }
    } else {
        int tt = bid - 2048;     // 0..255: A^T tiles
        int bx = tt & 15, by = tt >> 4;
        int tx = tid & 31, ty = tid >> 5;
        #pragma unroll
        for (int i = 0; i < 32; i += 8)
            tile[ty + i][tx] = a.A[(size_t)(by * 32 + ty + i) * 512 + bx * 32 + tx];
        __syncthreads();
        #pragma unroll
        for (int i = 0; i < 32; i += 8)
            a.ATb[(size_t)(bx * 32 + ty + i) * 512 + by * 32 + tx] = f2b(tile[tx][ty + i]);
    }
}

// ---------------------------------------------------------------------------
// Fused pointwise: Taylor accum (K=12) + LSTM cell.
// combb (256 x 2048): [hssm | h_new s=0..2]
// ---------------------------------------------------------------------------
__global__ void pointwise_fused(
    const float* __restrict__ Tm, const float* __restrict__ coeff,
    const float* __restrict__ h_prev, const float* __restrict__ delta,
    const float* __restrict__ Bx, float* __restrict__ hssm,
    unsigned short* __restrict__ combb,
    const float* __restrict__ gates, const float* __restrict__ bih,
    const float* __restrict__ bhh, const float* __restrict__ cin,
    const float* __restrict__ decays,
    float* __restrict__ hout, float* __restrict__ cout)
{
    int idx4 = blockIdx.x * 256 + threadIdx.x;
    int base = idx4 * 4;
    if (base < 131072) {
        int b = base >> 9, i = base & 511;
        const float* Tr = Tm + (size_t)b * (KMAX * DIM) + i;
        float4v a = *(const float4v*)(h_prev + base);
        #pragma unroll
        for (int k = 1; k <= KMAX; ++k) {
            float c = coeff[k * 256 + b];
            float4v t = *(const float4v*)(Tr + (size_t)(k - 1) * DIM);
            a.x += c * t.x; a.y += c * t.y; a.z += c * t.z; a.w += c * t.w;
        }
        float dl = delta[b];
        float4v bx = *(const float4v*)(Bx + base);
        a.x += dl * bx.x; a.y += dl * bx.y; a.z += dl * bx.z; a.w += dl * bx.w;
        *(float4v*)(hssm + base) = a;
        *(ushort4v*)(combb + (size_t)b * 2048 + i) = f2b4(a);
    } else {
        int i2 = base - 131072;
        int s = i2 / (NB * DIM);
        int r = i2 - s * (NB * DIM);
        int b = r >> 9, d = r & 511;
        const float* gr = gates + (size_t)s * 524288 + (size_t)b * 2048 + d;
        const float* bi = bih + s * 2048 + d;
        const float* bh = bhh + s * 2048 + d;
        float4v gi = *(const float4v*)(gr);
        float4v gf = *(const float4v*)(gr + 512);
        float4v gg = *(const float4v*)(gr + 1024);
        float4v go = *(const float4v*)(gr + 1536);
        float4v bi0 = *(const float4v*)(bi),        bh0 = *(const float4v*)(bh);
        float4v bi1 = *(const float4v*)(bi + 512),  bh1 = *(const float4v*)(bh + 512);
        float4v bi2 = *(const float4v*)(bi + 1024), bh2 = *(const float4v*)(bh + 1024);
        float4v bi3 = *(const float4v*)(bi + 1536), bh3 = *(const float4v*)(bh + 1536);
        float4v c = *(const float4v*)(cin + i2);
        float dec = decays[s];
        float4v hn, cn;
        #pragma unroll
        for (int j = 0; j < 4; ++j) {
            float vgi = ((const float*)&gi)[j] + ((const float*)&bi0)[j] + ((const float*)&bh0)[j];
            float vgf = ((const float*)&gf)[j] + ((const float*)&bi1)[j] + ((const float*)&bh1)[j];
            float vgg = ((const float*)&gg)[j] + ((const float*)&bi2)[j] + ((const float*)&bh2)[j];
            float vgo = ((const float*)&go)[j] + ((const float*)&bi3)[j] + ((const float*)&bh3)[j];
            float ig = 1.f / (1.f + expf(-vgi));
            float fg = 1.f / (1.f + expf(-vgf));
            float g_ = tanhf(vgg);
            float og = 1.f / (1.f + expf(-vgo));
            float cc = ((const float*)&c)[j];
            float craw = fg * cc + ig * g_;
            ((float*)&hn)[j] = og * tanhf(craw);
            ((float*)&cn)[j] = dec * cc + (1.f - dec) * craw;
        }
        *(float4v*)(hout + i2) = hn;
        *(float4v*)(cout + i2) = cn;
        *(ushort4v*)(combb + (size_t)b * 2048 + 512 + s * 512 + d) = f2b4(hn);
    }
}

// ---------------------------------------------------------------------------
// Fused tail: attn softmax + fused = ctx.aout_w^T + aout_b
//           + out = LN(projA + fused.P2^T).  One block per row b.
// ---------------------------------------------------------------------------
__global__ __launch_bounds__(256) void tail_kernel(
    const unsigned short* __restrict__ qb, const unsigned short* __restrict__ kvb,
    const unsigned short* __restrict__ aout_wb, const float* __restrict__ aout_b,
    const unsigned short* __restrict__ P2b, const float* __restrict__ projA,
    const float* __restrict__ fin_g, const float* __restrict__ fin_beta,
    float* __restrict__ outp)
{
    __shared__ float ctxs[512];
    __shared__ float fusedl[512];
    __shared__ float totals[512];
    __shared__ float sb1[4], sb2[4];
    int b = blockIdx.x, tid = threadIdx.x;

    if (tid < 128) {
        int h = tid >> 4, sub = (tid & 15) * 4;
        int col = h * 64 + sub;
        ushort4v q4 = *(const ushort4v*)(qb + (size_t)b * 512 + col);
        float qf[4] = { b2f(q4.x), b2f(q4.y), b2f(q4.z), b2f(q4.w) };
        float p[3];
        ushort4v k4[3], v4[3];
        #pragma unroll
        for (int s = 0; s < 3; ++s) {
            k4[s] = *(const ushort4v*)(kvb + (size_t)s * 262144 + (size_t)b * 1024 + col);
            v4[s] = *(const ushort4v*)(kvb + (size_t)s * 262144 + (size_t)b * 1024 + 512 + col);
            p[s] = qf[0] * b2f(k4[s].x) + qf[1] * b2f(k4[s].y)
                 + qf[2] * b2f(k4[s].z) + qf[3] * b2f(k4[s].w);
        }
        #pragma unroll
        for (int off = 1; off < 16; off <<= 1) {
            p[0] += __shfl_xor(p[0], off);
            p[1] += __shfl_xor(p[1], off);
            p[2] += __shfl_xor(p[2], off);
        }
        const float scale = 0.125f;
        float p0 = p[0] * scale, p1 = p[1] * scale, p2 = p[2] * scale;
        float m = fmaxf(p0, fmaxf(p1, p2));
        float w0 = expf(p0 - m), w1 = expf(p1 - m), w2 = expf(p2 - m);
        float invs = 1.f / (w0 + w1 + w2);
        ctxs[col + 0] = (w0 * b2f(v4[0].x) + w1 * b2f(v4[1].x) + w2 * b2f(v4[2].x)) * invs;
        ctxs[col + 1] = (w0 * b2f(v4[0].y) + w1 * b2f(v4[1].y) + w2 * b2f(v4[2].y)) * invs;
        ctxs[col + 2] = (w0 * b2f(v4[0].z) + w1 * b2f(v4[1].z) + w2 * b2f(v4[2].z)) * invs;
        ctxs[col + 3] = (w0 * b2f(v4[0].w) + w1 * b2f(v4[1].w) + w2 * b2f(v4[2].w)) * invs;
    }
    __syncthreads();

    // fused[j] = aout_b[j] + sum_k ctx[k] * aout_w[j,k]
    for (int jj = tid; jj < 512; jj += 256) {
        float acc = aout_b[jj];
        const unsigned short* wr = aout_wb + (size_t)jj * 512;
        for (int k = 0; k < 512; k += 8) {
            ushort4v w0 = *(const ushort4v*)(wr + k);
            ushort4v w1 = *(const ushort4v*)(wr + k + 4);
            acc += ctxs[k+0]*b2f(w0.x) + ctxs[k+1]*b2f(w0.y)
                 + ctxs[k+2]*b2f(w0.z) + ctxs[k+3]*b2f(w0.w)
                 + ctxs[k+4]*b2f(w1.x) + ctxs[k+5]*b2f(w1.y)
                 + ctxs[k+6]*b2f(w1.z) + ctxs[k+7]*b2f(w1.w);
        }
        fusedl[jj] = acc;
    }
    __syncthreads();

    // totals[i] = projA[b,i] + sum_j fused[j] * P2[i,j]
    for (int ii = tid; ii < 512; ii += 256) {
        float acc = projA[(size_t)b * 512 + ii];
        const unsigned short* pr = P2b + (size_t)ii * 512;
        for (int j = 0; j < 512; j += 8) {
            ushort4v w0 = *(const ushort4v*)(pr + j);
            ushort4v w1 = *(const ushort4v*)(pr + j + 4);
            acc += fusedl[j+0]*b2f(w0.x) + fusedl[j+1]*b2f(w0.y)
                 + fusedl[j+2]*b2f(w0.z) + fusedl[j+3]*b2f(w0.w)
                 + fusedl[j+4]*b2f(w1.x) + fusedl[j+5]*b2f(w1.y)
                 + fusedl[j+6]*b2f(w1.z) + fusedl[j+7]*b2f(w1.w);
        }
        totals[ii] = acc;
    }
    __syncthreads();

    float x0 = totals[tid], x1 = totals[tid + 256];
    float s = x0 + x1, q = x0 * x0 + x1 * x1;
    block_reduce2(s, q, sb1, sb2);
    float mean = s * (1.f / DIM);
    float var  = q * (1.f / DIM) - mean * mean;
    float inv  = rsqrtf(var + 1e-5f);
    outp[(size_t)b * DIM + tid]       = (x0 - mean) * inv * fin_g[tid]       + fin_beta[tid];
    outp[(size_t)b * DIM + tid + 256] = (x1 - mean) * inv * fin_g[tid + 256] + fin_beta[tid + 256];
}

// ---------------------------------------------------------------------------
extern "C" void kernel_launch(void* const* d_in, const int* in_sizes, int n_in,
                              void* d_out, int out_size, void* d_ws, size_t ws_size,
                              hipStream_t stream)
{
    const float* x        = (const float*)d_in[0];
    const float* h_prev   = (const float*)d_in[1];
    const float* lstm_h   = (const float*)d_in[2];
    const float* lstm_c   = (const float*)d_in[3];
    const float* A        = (const float*)d_in[4];
    const float* Bm       = (const float*)d_in[5];
    const float* dn_w1    = (const float*)d_in[6];
    const float* dn_b1    = (const float*)d_in[7];
    const float* dn_g     = (const float*)d_in[8];
    const float* dn_beta  = (const float*)d_in[9];
    const float* dn_w2    = (const float*)d_in[10];
    const float* dn_b2    = (const float*)d_in[11];
    const float* wih      = (const float*)d_in[12];
    const float* whh      = (const float*)d_in[13];
    const float* bih      = (const float*)d_in[14];
    const float* bhh      = (const float*)d_in[15];
    const float* decays   = (const float*)d_in[16];
    const float* ain_w    = (const float*)d_in[17];
    const float* ain_b    = (const float*)d_in[18];
    const float* aout_w   = (const float*)d_in[19];
    const float* aout_b   = (const float*)d_in[20];
    const float* proj_w   = (const float*)d_in[21];
    const float* proj_b   = (const float*)d_in[22];
    const float* proj_g   = (const float*)d_in[23];
    const float* proj_bt  = (const float*)d_in[24];

    float* out  = (float*)d_out;
    float* hssm = out + 131072;
    float* hnew = out + 262144;
    float* cnew = out + 655360;

    // ---- workspace (bf16 section) ----
    unsigned short* us = (unsigned short*)d_ws;
    unsigned short* hpb     = us;                  // 131072
    unsigned short* ATb     = us + 131072;         // 262144
    unsigned short* dn_w1b  = us + 393216;         // 262144
    unsigned short* Bmb     = us + 655360;         // 262144
    unsigned short* ain_wb  = us + 917504;         // 786432
    unsigned short* proj_wb = us + 1703936;        // 1048576 (512x2048 packed [P0|P1])
    unsigned short* P2b     = us + 2752512;        // 262144 (proj_w cols 512:1024)
    unsigned short* aout_wb = us + 3014656;        // 262144
    unsigned short* Pw      = us + 3276800;        // 12*262144 [A^1..A^12]
    unsigned short* Qa      = us + 6422528;        // 262144
    unsigned short* Qb      = us + 6684672;        // 262144
    unsigned short* Wcat    = us + 6946816;        // 6291456
    unsigned short* Xcat    = us + 13238272;       // 786432
    unsigned short* combb   = us + 14024704;       // 524288 (256x2048) [hssm|hnew*3]
    unsigned short* qb      = us + 14548992;       // 131072
    unsigned short* kvb     = us + 14680064;       // 786432
    // ---- fp32 section ----
    float* fbase  = (float*)(us + 15466496);
    float* pre1   = fbase;                         // 131072 (reused as projout)
    float* delta  = fbase + 131072;                // 256
    float* coeff  = fbase + 131328;                // 13*256
    float* Bx     = fbase + 134656;                // 131072
    float* Tm     = fbase + 265728;                // 256*6144 = 1572864
    float* gates  = fbase + 1838592;               // 1572864
    float* projout = pre1;

    LnParams lpOff; lpOff.pre = nullptr; lpOff.g = nullptr; lpOff.beta = nullptr;
    lpOff.w2 = nullptr; lpOff.b2 = nullptr; lpOff.delta = nullptr; lpOff.coeff = nullptr;
    lpOff.lnd_y = -1;

    // ---- 1. unified prep (14 segments + A^T) ----
    PrepArgs pa;
    int sidx = 0;
    auto LIN = [&](const float* s, unsigned short* d, int n4) {
        pa.sA[sidx]=s; pa.sB[sidx]=s; pa.dst[sidx]=d; pa.n4[sidx]=n4;
        pa.dRL4[sidx]=n4; pa.sRLA4[sidx]=0; pa.sRLB4[sidx]=0;
        pa.half4[sidx]=n4; pa.offA[sidx]=0; ++sidx;
    };
    LIN(h_prev, hpb,     32768);
    LIN(A,      Pw,      65536);
    LIN(dn_w1,  dn_w1b,  65536);
    LIN(Bm,     Bmb,     65536);
    LIN(ain_w,  ain_wb,  196608);
    LIN(aout_w, aout_wb, 65536);
    // proj_wb: 512 rows x 2048 packed [proj_w cols 0:512 | proj_w cols 1024:2560]
    pa.sA[sidx]=proj_w; pa.sB[sidx]=proj_w + 1024; pa.dst[sidx]=proj_wb; pa.n4[sidx]=262144;
    pa.dRL4[sidx]=512; pa.sRLA4[sidx]=640; pa.sRLB4[sidx]=640; pa.half4[sidx]=128; pa.offA[sidx]=0; ++sidx;
    // P2b: proj_w cols 512:1024 -> 512x512
    pa.sA[sidx]=proj_w; pa.sB[sidx]=proj_w; pa.dst[sidx]=P2b; pa.n4[sidx]=65536;
    pa.dRL4[sidx]=128; pa.sRLA4[sidx]=640; pa.sRLB4[sidx]=640; pa.half4[sidx]=128; pa.offA[sidx]=128; ++sidx;
    // Wcat_s = [wih_s | whh_s]
    for (int s = 0; s < 3; ++s) {
        pa.sA[sidx]=wih + (size_t)s*1048576; pa.sB[sidx]=whh + (size_t)s*1048576;
        pa.dst[sidx]=Wcat + (size_t)s*2097152; pa.n4[sidx]=524288;
        pa.dRL4[sidx]=256; pa.sRLA4[sidx]=128; pa.sRLB4[sidx]=128; pa.half4[sidx]=128; pa.offA[sidx]=0; ++sidx;
    }
    // Xcat_s = [x | lstm_h_s]
    for (int s = 0; s < 3; ++s) {
        pa.sA[sidx]=x; pa.sB[sidx]=lstm_h + (size_t)s*131072;
        pa.dst[sidx]=Xcat + (size_t)s*262144; pa.n4[sidx]=65536;
        pa.dRL4[sidx]=256; pa.sRLA4[sidx]=128; pa.sRLB4[sidx]=128; pa.half4[sidx]=128; pa.offA[sidx]=0; ++sidx;
    }
    pa.A = A; pa.ATb = ATb;
    prep_kernel<<<2304, 256, 0, stream>>>(pa);

    GemmArgs ga;
    // ---- 2. batch1: dense1, Bx, G1 (A^2 + Q2), LSTM x3 ----
    ga.d[0] = { Xcat, dn_w1b, dn_b1, pre1, nullptr, nullptr, 256, 512, 512, 1024, 512, 512, 0, 0 };
    ga.d[1] = { Xcat, Bmb,    nullptr, Bx,  nullptr, nullptr, 256, 512, 512, 1024, 512, 512, 0, 0 };
    ga.d[2] = { Pw, ATb, nullptr, nullptr, Pw + 1*262144, Qa, 512, 512, 512, 512, 512, 512, 0, 0 };
    for (int s = 0; s < 3; ++s)
        ga.d[3 + s] = { Xcat + (size_t)s * 262144, Wcat + (size_t)s * 2097152, nullptr,
                        gates + (size_t)s * 524288, nullptr, nullptr, 256, 2048, 1024, 1024, 1024, 2048, 0, 0 };
    gemm_mfma<<<dim3(128, 6), 256, 0, stream>>>(ga, lpOff);

    // ---- 3. G2 [A^3,A^4]+Q4  +  fused LN/GELU/delta (y==1) ----
    LnParams lp1 = { pre1, dn_g, dn_beta, dn_w2, dn_b2, delta, coeff, 1 };
    ga.d[0] = { Pw, Qa, nullptr, nullptr, Pw + 2*262144, Qb, 1024, 512, 512, 512, 512, 512, 512, 0 };
    gemm_mfma<<<dim3(256, 2), 256, 0, stream>>>(ga, lp1);

    // ---- 4. G3 [A^5..A^8]+Q8 ----
    ga.d[0] = { Pw, Qb, nullptr, nullptr, Pw + 4*262144, Qa, 2048, 512, 512, 512, 512, 512, 1536, 0 };
    gemm_mfma<<<dim3(256, 1), 256, 0, stream>>>(ga, lpOff);

    // ---- 5. G4 [A^9..A^12] + Taylor1 (k=1..8) ----
    ga.d[0] = { Pw, Qa, nullptr, nullptr, Pw + 8*262144, nullptr, 2048, 512, 512, 512, 512, 512, 0, 0 };
    ga.d[1] = { hpb, Pw, nullptr, Tm, nullptr, nullptr, 256, 4096, 512, 512, 512, 6144, 0, 0 };
    gemm_mfma<<<dim3(256, 2), 256, 0, stream>>>(ga, lpOff);

    // ---- 6. Taylor2 (k=9..12) ----
    ga.d[0] = { hpb, Pw + 8*262144, nullptr, Tm + 4096, nullptr, nullptr, 256, 2048, 512, 512, 512, 6144, 0, 0 };
    gemm_mfma<<<dim3(128, 1), 256, 0, stream>>>(ga, lpOff);

    // ---- 7. fused pointwise (taylor accum + lstm cell) ----
    pointwise_fused<<<512, 256, 0, stream>>>(Tm, coeff, h_prev, delta, Bx, hssm, combb,
                                             gates, bih, bhh, lstm_c, decays, hnew, cnew);

    // ---- 8. q + kv x3 + projA (K=2048 over [hssm|h_new]) ----
    ga.d[0] = { combb, ain_wb, ain_b, nullptr, qb, nullptr, 256, 512, 512, 2048, 512, 512, 0, 0 };
    for (int s = 0; s < 3; ++s)
        ga.d[1 + s] = { combb + 512 + (size_t)s * 512, ain_wb + 262144, ain_b + 512,
                        nullptr, kvb + (size_t)s * 262144, nullptr, 256, 1024, 512, 2048, 512, 1024, 0, 0 };
    ga.d[4] = { combb, proj_wb, proj_b, projout, nullptr, nullptr, 256, 512, 2048, 2048, 2048, 512, 0, 0 };
    gemm_mfma<<<dim3(64, 5), 256, 0, stream>>>(ga, lpOff);

    // ---- 9. fused tail: attn + out-proj + proj-slice + final LN ----
    tail_kernel<<<256, 256, 0, stream>>>(qb, kvb, aout_wb, aout_b, P2b, projout,
                                         proj_g, proj_bt, out);
}

// Round 12
// 234.163 us; speedup vs baseline: 5.6499x; 1.0496x over previous
//
#include <hip/hip_runtime.h>
#include <math.h>

#define DIM 512
#define NB 256
#define KMAX 12   // Taylor terms (powers A^1..A^12)

using bf16x8 = __attribute__((ext_vector_type(8))) short;
using f32x4  = __attribute__((ext_vector_type(4))) float;
using float4v = __attribute__((ext_vector_type(4))) float;
using ushort4v = __attribute__((ext_vector_type(4))) unsigned short;

__device__ __forceinline__ unsigned short f2b(float f) {
    union { float f; unsigned int u; } v; v.f = f;
    unsigned int r = v.u + 0x7fffu + ((v.u >> 16) & 1u);
    return (unsigned short)(r >> 16);
}
__device__ __forceinline__ float b2f(unsigned short u) {
    union { unsigned int u; float f; } v; v.u = ((unsigned int)u) << 16;
    return v.f;
}
__device__ __forceinline__ ushort4v f2b4(float4v v) {
    ushort4v o;
    o.x = f2b(v.x); o.y = f2b(v.y); o.z = f2b(v.z); o.w = f2b(v.w);
    return o;
}

__device__ __forceinline__ void block_reduce2(float& s, float& q, float* sb1, float* sb2)
{
    int tid = threadIdx.x;
    #pragma unroll
    for (int off = 32; off > 0; off >>= 1) {
        s += __shfl_down(s, off);
        q += __shfl_down(q, off);
    }
    if ((tid & 63) == 0) { sb1[tid >> 6] = s; sb2[tid >> 6] = q; }
    __syncthreads();
    s = sb1[0] + sb1[1] + sb1[2] + sb1[3];
    q = sb2[0] + sb2[1] + sb2[2] + sb2[3];
    __syncthreads();
}

// ---------------------------------------------------------------------------
// Batched bf16 MFMA GEMM, BK=128 (4 serial drains for K=512 instead of 8).
// C[m,n]=sum_k X[m,k]W[n,k]+b.  acc=1: Cf+=.  Ct: transposed dual-write.
// lp.lnd_y == blockIdx.y -> fused LN/GELU/delta branch.  K % 128 == 0.
// ---------------------------------------------------------------------------
struct GemmDesc {
    const unsigned short* X;
    const unsigned short* W;
    const float* bias;
    float* Cf;
    unsigned short* Cb;
    unsigned short* Ct;
    int M, N, K, ldX, ldW, ldC, tr_row0, acc;
};
struct GemmArgs { GemmDesc d[6]; };
struct LnParams {
    const float* pre; const float* g; const float* beta;
    const float* w2; const float* b2; float* delta; float* coeff;
    int lnd_y;
};

__global__ __launch_bounds__(256) void gemm_mfma(GemmArgs args, LnParams lp)
{
    __shared__ unsigned short lsA[2][8192];
    __shared__ unsigned short lsB[2][8192];
    __shared__ float sb1[4], sb2[4];

    if ((int)blockIdx.y == lp.lnd_y) {
        int b = blockIdx.x, tid = threadIdx.x;
        int i0 = tid, i1 = tid + 256;
        float x0 = lp.pre[(size_t)b * DIM + i0];
        float x1 = lp.pre[(size_t)b * DIM + i1];
        float s = x0 + x1, q = x0 * x0 + x1 * x1;
        block_reduce2(s, q, sb1, sb2);
        float mean = s * (1.f / DIM);
        float var  = q * (1.f / DIM) - mean * mean;
        float inv  = rsqrtf(var + 1e-5f);
        float y0 = (x0 - mean) * inv * lp.g[i0] + lp.beta[i0];
        float y1 = (x1 - mean) * inv * lp.g[i1] + lp.beta[i1];
        float h0 = 0.5f * y0 * (1.f + erff(y0 * 0.70710678118654752f));
        float h1 = 0.5f * y1 * (1.f + erff(y1 * 0.70710678118654752f));
        float p = h0 * lp.w2[i0] + h1 * lp.w2[i1];
        float dummy = 0.f;
        block_reduce2(p, dummy, sb1, sb2);
        if (tid == 0) {
            float z = p + lp.b2[0];
            float d = (z > 20.f) ? z : log1pf(expf(z));
            lp.delta[b] = d;
            float c = 1.f;
            lp.coeff[b] = 1.f;
            for (int k = 1; k <= KMAX; ++k) { c *= d / (float)k; lp.coeff[k * 256 + b] = c; }
        }
        return;
    }

    GemmDesc de = args.d[blockIdx.y];
    int tn = de.N >> 6;
    int tiles = (de.M >> 6) * tn;
    int t = blockIdx.x;
    if (t >= tiles) return;
    int m0 = (t / tn) << 6;
    int n0 = (t % tn) << 6;

    int tid = threadIdx.x;
    int w = tid >> 6;
    int l = tid & 63;
    int nkt = de.K >> 7;      // BK=128

    int srow = w * 16 + (l >> 2);
    int schk = l & 3;
    const unsigned short* gA = de.X + (size_t)(m0 + srow) * de.ldX + schk * 8;
    const unsigned short* gB = de.W + (size_t)(n0 + srow) * de.ldW + schk * 8;
    unsigned short* lA = &lsA[0][(w * 64 + l) * 8];
    unsigned short* lB = &lsB[0][(w * 64 + l) * 8];

    // stage one BK=128 buffer: 4 passes of 32 k each, per matrix
#define STAGE(bufi, kt)                                                          \
    do {                                                                         \
        for (int hh = 0; hh < 4; ++hh) {                                         \
            __builtin_amdgcn_global_load_lds(                                    \
                (const __attribute__((address_space(1))) unsigned int*)(gA + (size_t)(kt) * 128 + hh * 32), \
                (__attribute__((address_space(3))) unsigned int*)(lA + (bufi) * 8192 + hh * 2048), 16, 0, 0); \
            __builtin_amdgcn_global_load_lds(                                    \
                (const __attribute__((address_space(1))) unsigned int*)(gB + (size_t)(kt) * 128 + hh * 32), \
                (__attribute__((address_space(3))) unsigned int*)(lB + (bufi) * 8192 + hh * 2048), 16, 0, 0); \
        }                                                                        \
    } while (0)

    int mbase = (w >> 1) * 32;
    int nbase = (w & 1) * 32;

    f32x4 acc[2][2];
    #pragma unroll
    for (int i = 0; i < 2; ++i)
        #pragma unroll
        for (int j = 0; j < 2; ++j)
            acc[i][j] = (f32x4){0.f, 0.f, 0.f, 0.f};

    int kg = l >> 4;
    int fr = l & 15;
    int aslot = (mbase * 4 + fr * 4 + kg) * 8;
    int bslot = (nbase * 4 + fr * 4 + kg) * 8;

    STAGE(0, 0);

    for (int kt = 0; kt < nkt; ++kt) {
        __syncthreads();
        if (kt + 1 < nkt) STAGE((kt + 1) & 1, kt + 1);

        const unsigned short* bufA = &lsA[kt & 1][0];
        const unsigned short* bufB = &lsB[kt & 1][0];
        #pragma unroll
        for (int h = 0; h < 4; ++h) {
            bf16x8 a0 = *(const bf16x8*)(bufA + h * 2048 + aslot);
            bf16x8 a1 = *(const bf16x8*)(bufA + h * 2048 + aslot + 512);
            bf16x8 b0 = *(const bf16x8*)(bufB + h * 2048 + bslot);
            bf16x8 b1 = *(const bf16x8*)(bufB + h * 2048 + bslot + 512);
            acc[0][0] = __builtin_amdgcn_mfma_f32_16x16x32_bf16(a0, b0, acc[0][0], 0, 0, 0);
            acc[0][1] = __builtin_amdgcn_mfma_f32_16x16x32_bf16(a0, b1, acc[0][1], 0, 0, 0);
            acc[1][0] = __builtin_amdgcn_mfma_f32_16x16x32_bf16(a1, b0, acc[1][0], 0, 0, 0);
            acc[1][1] = __builtin_amdgcn_mfma_f32_16x16x32_bf16(a1, b1, acc[1][1], 0, 0, 0);
        }
    }

    #pragma unroll
    for (int mi = 0; mi < 2; ++mi) {
        #pragma unroll
        for (int ni = 0; ni < 2; ++ni) {
            int col = n0 + nbase + ni * 16 + fr;
            float bv = de.bias ? de.bias[col] : 0.f;
            #pragma unroll
            for (int r = 0; r < 4; ++r) {
                int row = m0 + mbase + mi * 16 + (l >> 4) * 4 + r;
                float v = acc[mi][ni][r] + bv;
                if (de.Cf) {
                    if (de.acc) de.Cf[(size_t)row * de.ldC + col] += v;
                    else        de.Cf[(size_t)row * de.ldC + col] = v;
                } else {
                    de.Cb[(size_t)row * de.ldC + col] = f2b(v);
                }
                if (de.Ct && row >= de.tr_row0)
                    de.Ct[(size_t)col * 512 + (row - de.tr_row0)] = f2b(v);
            }
        }
    }
#undef STAGE
}

// ---------------------------------------------------------------------------
// Unified prep: 14 convert segments + A^T transpose.  Grid 2304 x 256.
// ---------------------------------------------------------------------------
#define NSEG 14
struct PrepArgs {
    const float* sA[NSEG]; const float* sB[NSEG]; unsigned short* dst[NSEG];
    int n4[NSEG], dRL4[NSEG], sRLA4[NSEG], sRLB4[NSEG], half4[NSEG], offA[NSEG];
    const float* A; unsigned short* ATb;
};
__global__ __launch_bounds__(256) void prep_kernel(PrepArgs a)
{
    __shared__ float tile[32][33];
    int bid = blockIdx.x, tid = threadIdx.x;
    if (bid < 2048) {
        const int gstride = 2048 * 256;
        int g0 = bid * 256 + tid;
        for (int seg = 0; seg < NSEG; ++seg) {
            int n4 = a.n4[seg];
            const float* sA = a.sA[seg];
            const float* sB = a.sB[seg];
            unsigned short* d = a.dst[seg];
            int dRL4 = a.dRL4[seg], sRLA4 = a.sRLA4[seg], sRLB4 = a.sRLB4[seg];
            int half4 = a.half4[seg], offA = a.offA[seg];
            for (int i = g0; i < n4; i += gstride) {
                int r = i / dRL4, c = i - r * dRL4;
                const float* src = (c < half4)
                    ? sA + ((size_t)r * sRLA4 + offA + c) * 4
                    : sB + ((size_t)r * sRLB4 + (c - half4)) * 4;
                float4v v = *(const float4v*)src;
                *(ushort4v*)(d + (size_t)i * 4) = f2b4(v);
            }
        }
    } else {
        int tt = bid - 2048;
        int bx = tt & 15, by = tt >> 4;
        int tx = tid & 31, ty = tid >> 5;
        #pragma unroll
        for (int i = 0; i < 32; i += 8)
            tile[ty + i][tx] = a.A[(size_t)(by * 32 + ty + i) * 512 + bx * 32 + tx];
        __syncthreads();
        #pragma unroll
        for (int i = 0; i < 32; i += 8)
            a.ATb[(size_t)(bx * 32 + ty + i) * 512 + by * 32 + tx] = f2b(tile[tx][ty + i]);
    }
}

// ---------------------------------------------------------------------------
// Fused pointwise: Taylor accum (K=12) + LSTM cell.
// combb (256 x 2048): [hssm | h_new s=0..2]
// ---------------------------------------------------------------------------
__global__ void pointwise_fused(
    const float* __restrict__ Tm, const float* __restrict__ coeff,
    const float* __restrict__ h_prev, const float* __restrict__ delta,
    const float* __restrict__ Bx, float* __restrict__ hssm,
    unsigned short* __restrict__ combb,
    const float* __restrict__ gates, const float* __restrict__ bih,
    const float* __restrict__ bhh, const float* __restrict__ cin,
    const float* __restrict__ decays,
    float* __restrict__ hout, float* __restrict__ cout)
{
    int idx4 = blockIdx.x * 256 + threadIdx.x;
    int base = idx4 * 4;
    if (base < 131072) {
        int b = base >> 9, i = base & 511;
        const float* Tr = Tm + (size_t)b * (KMAX * DIM) + i;
        float4v a = *(const float4v*)(h_prev + base);
        #pragma unroll
        for (int k = 1; k <= KMAX; ++k) {
            float c = coeff[k * 256 + b];
            float4v t = *(const float4v*)(Tr + (size_t)(k - 1) * DIM);
            a.x += c * t.x; a.y += c * t.y; a.z += c * t.z; a.w += c * t.w;
        }
        float dl = delta[b];
        float4v bx = *(const float4v*)(Bx + base);
        a.x += dl * bx.x; a.y += dl * bx.y; a.z += dl * bx.z; a.w += dl * bx.w;
        *(float4v*)(hssm + base) = a;
        *(ushort4v*)(combb + (size_t)b * 2048 + i) = f2b4(a);
    } else {
        int i2 = base - 131072;
        int s = i2 / (NB * DIM);
        int r = i2 - s * (NB * DIM);
        int b = r >> 9, d = r & 511;
        const float* gr = gates + (size_t)s * 524288 + (size_t)b * 2048 + d;
        const float* bi = bih + s * 2048 + d;
        const float* bh = bhh + s * 2048 + d;
        float4v gi = *(const float4v*)(gr);
        float4v gf = *(const float4v*)(gr + 512);
        float4v gg = *(const float4v*)(gr + 1024);
        float4v go = *(const float4v*)(gr + 1536);
        float4v bi0 = *(const float4v*)(bi),        bh0 = *(const float4v*)(bh);
        float4v bi1 = *(const float4v*)(bi + 512),  bh1 = *(const float4v*)(bh + 512);
        float4v bi2 = *(const float4v*)(bi + 1024), bh2 = *(const float4v*)(bh + 1024);
        float4v bi3 = *(const float4v*)(bi + 1536), bh3 = *(const float4v*)(bh + 1536);
        float4v c = *(const float4v*)(cin + i2);
        float dec = decays[s];
        float4v hn, cn;
        #pragma unroll
        for (int j = 0; j < 4; ++j) {
            float vgi = ((const float*)&gi)[j] + ((const float*)&bi0)[j] + ((const float*)&bh0)[j];
            float vgf = ((const float*)&gf)[j] + ((const float*)&bi1)[j] + ((const float*)&bh1)[j];
            float vgg = ((const float*)&gg)[j] + ((const float*)&bi2)[j] + ((const float*)&bh2)[j];
            float vgo = ((const float*)&go)[j] + ((const float*)&bi3)[j] + ((const float*)&bh3)[j];
            float ig = 1.f / (1.f + expf(-vgi));
            float fg = 1.f / (1.f + expf(-vgf));
            float g_ = tanhf(vgg);
            float og = 1.f / (1.f + expf(-vgo));
            float cc = ((const float*)&c)[j];
            float craw = fg * cc + ig * g_;
            ((float*)&hn)[j] = og * tanhf(craw);
            ((float*)&cn)[j] = dec * cc + (1.f - dec) * craw;
        }
        *(float4v*)(hout + i2) = hn;
        *(float4v*)(cout + i2) = cn;
        *(ushort4v*)(combb + (size_t)b * 2048 + 512 + s * 512 + d) = f2b4(hn);
    }
}

// ---------------------------------------------------------------------------
// Fused tail: attn softmax + fused = ctx.aout_w^T + aout_b
//           + out = LN(projA + fused.P2^T).  One block per row b.
// ---------------------------------------------------------------------------
__global__ __launch_bounds__(256) void tail_kernel(
    const unsigned short* __restrict__ qb, const unsigned short* __restrict__ kvb,
    const unsigned short* __restrict__ aout_wb, const float* __restrict__ aout_b,
    const unsigned short* __restrict__ P2b, const float* __restrict__ projA,
    const float* __restrict__ fin_g, const float* __restrict__ fin_beta,
    float* __restrict__ outp)
{
    __shared__ float ctxs[512];
    __shared__ float fusedl[512];
    __shared__ float totals[512];
    __shared__ float sb1[4], sb2[4];
    int b = blockIdx.x, tid = threadIdx.x;

    if (tid < 128) {
        int h = tid >> 4, sub = (tid & 15) * 4;
        int col = h * 64 + sub;
        ushort4v q4 = *(const ushort4v*)(qb + (size_t)b * 512 + col);
        float qf[4] = { b2f(q4.x), b2f(q4.y), b2f(q4.z), b2f(q4.w) };
        float p[3];
        ushort4v k4[3], v4[3];
        #pragma unroll
        for (int s = 0; s < 3; ++s) {
            k4[s] = *(const ushort4v*)(kvb + (size_t)s * 262144 + (size_t)b * 1024 + col);
            v4[s] = *(const ushort4v*)(kvb + (size_t)s * 262144 + (size_t)b * 1024 + 512 + col);
            p[s] = qf[0] * b2f(k4[s].x) + qf[1] * b2f(k4[s].y)
                 + qf[2] * b2f(k4[s].z) + qf[3] * b2f(k4[s].w);
        }
        #pragma unroll
        for (int off = 1; off < 16; off <<= 1) {
            p[0] += __shfl_xor(p[0], off);
            p[1] += __shfl_xor(p[1], off);
            p[2] += __shfl_xor(p[2], off);
        }
        const float scale = 0.125f;
        float p0 = p[0] * scale, p1 = p[1] * scale, p2 = p[2] * scale;
        float m = fmaxf(p0, fmaxf(p1, p2));
        float w0 = expf(p0 - m), w1 = expf(p1 - m), w2 = expf(p2 - m);
        float invs = 1.f / (w0 + w1 + w2);
        ctxs[col + 0] = (w0 * b2f(v4[0].x) + w1 * b2f(v4[1].x) + w2 * b2f(v4[2].x)) * invs;
        ctxs[col + 1] = (w0 * b2f(v4[0].y) + w1 * b2f(v4[1].y) + w2 * b2f(v4[2].y)) * invs;
        ctxs[col + 2] = (w0 * b2f(v4[0].z) + w1 * b2f(v4[1].z) + w2 * b2f(v4[2].z)) * invs;
        ctxs[col + 3] = (w0 * b2f(v4[0].w) + w1 * b2f(v4[1].w) + w2 * b2f(v4[2].w)) * invs;
    }
    __syncthreads();

    for (int jj = tid; jj < 512; jj += 256) {
        float acc = aout_b[jj];
        const unsigned short* wr = aout_wb + (size_t)jj * 512;
        for (int k = 0; k < 512; k += 8) {
            ushort4v w0 = *(const ushort4v*)(wr + k);
            ushort4v w1 = *(const ushort4v*)(wr + k + 4);
            acc += ctxs[k+0]*b2f(w0.x) + ctxs[k+1]*b2f(w0.y)
                 + ctxs[k+2]*b2f(w0.z) + ctxs[k+3]*b2f(w0.w)
                 + ctxs[k+4]*b2f(w1.x) + ctxs[k+5]*b2f(w1.y)
                 + ctxs[k+6]*b2f(w1.z) + ctxs[k+7]*b2f(w1.w);
        }
        fusedl[jj] = acc;
    }
    __syncthreads();

    for (int ii = tid; ii < 512; ii += 256) {
        float acc = projA[(size_t)b * 512 + ii];
        const unsigned short* pr = P2b + (size_t)ii * 512;
        for (int j = 0; j < 512; j += 8) {
            ushort4v w0 = *(const ushort4v*)(pr + j);
            ushort4v w1 = *(const ushort4v*)(pr + j + 4);
            acc += fusedl[j+0]*b2f(w0.x) + fusedl[j+1]*b2f(w0.y)
                 + fusedl[j+2]*b2f(w0.z) + fusedl[j+3]*b2f(w0.w)
                 + fusedl[j+4]*b2f(w1.x) + fusedl[j+5]*b2f(w1.y)
                 + fusedl[j+6]*b2f(w1.z) + fusedl[j+7]*b2f(w1.w);
        }
        totals[ii] = acc;
    }
    __syncthreads();

    float x0 = totals[tid], x1 = totals[tid + 256];
    float s = x0 + x1, q = x0 * x0 + x1 * x1;
    block_reduce2(s, q, sb1, sb2);
    float mean = s * (1.f / DIM);
    float var  = q * (1.f / DIM) - mean * mean;
    float inv  = rsqrtf(var + 1e-5f);
    outp[(size_t)b * DIM + tid]       = (x0 - mean) * inv * fin_g[tid]       + fin_beta[tid];
    outp[(size_t)b * DIM + tid + 256] = (x1 - mean) * inv * fin_g[tid + 256] + fin_beta[tid + 256];
}

// ---------------------------------------------------------------------------
extern "C" void kernel_launch(void* const* d_in, const int* in_sizes, int n_in,
                              void* d_out, int out_size, void* d_ws, size_t ws_size,
                              hipStream_t stream)
{
    const float* x        = (const float*)d_in[0];
    const float* h_prev   = (const float*)d_in[1];
    const float* lstm_h   = (const float*)d_in[2];
    const float* lstm_c   = (const float*)d_in[3];
    const float* A        = (const float*)d_in[4];
    const float* Bm       = (const float*)d_in[5];
    const float* dn_w1    = (const float*)d_in[6];
    const float* dn_b1    = (const float*)d_in[7];
    const float* dn_g     = (const float*)d_in[8];
    const float* dn_beta  = (const float*)d_in[9];
    const float* dn_w2    = (const float*)d_in[10];
    const float* dn_b2    = (const float*)d_in[11];
    const float* wih      = (const float*)d_in[12];
    const float* whh      = (const float*)d_in[13];
    const float* bih      = (const float*)d_in[14];
    const float* bhh      = (const float*)d_in[15];
    const float* decays   = (const float*)d_in[16];
    const float* ain_w    = (const float*)d_in[17];
    const float* ain_b    = (const float*)d_in[18];
    const float* aout_w   = (const float*)d_in[19];
    const float* aout_b   = (const float*)d_in[20];
    const float* proj_w   = (const float*)d_in[21];
    const float* proj_b   = (const float*)d_in[22];
    const float* proj_g   = (const float*)d_in[23];
    const float* proj_bt  = (const float*)d_in[24];

    float* out  = (float*)d_out;
    float* hssm = out + 131072;
    float* hnew = out + 262144;
    float* cnew = out + 655360;

    // ---- workspace (bf16 section) ----
    unsigned short* us = (unsigned short*)d_ws;
    unsigned short* hpb     = us;                  // 131072
    unsigned short* ATb     = us + 131072;         // 262144
    unsigned short* dn_w1b  = us + 393216;         // 262144
    unsigned short* Bmb     = us + 655360;         // 262144
    unsigned short* ain_wb  = us + 917504;         // 786432
    unsigned short* proj_wb = us + 1703936;        // 1048576 (512x2048 packed [P0|P1])
    unsigned short* P2b     = us + 2752512;        // 262144
    unsigned short* aout_wb = us + 3014656;        // 262144
    unsigned short* Pw      = us + 3276800;        // 8*262144 [A^1..A^8]
    unsigned short* Qa      = us + 5373952;        // 262144
    unsigned short* Qb      = us + 5636096;        // 262144
    unsigned short* Wcat    = us + 5898240;        // 6291456
    unsigned short* Xcat    = us + 12189696;       // 786432
    unsigned short* combb   = us + 12976128;       // 524288 (256x2048) [hssm|hnew*3]
    unsigned short* qb      = us + 13500416;       // 131072
    unsigned short* kvb     = us + 13631488;       // 786432
    unsigned short* U8b     = us + 14417920;       // 131072 (bf16 A^8 h)
    // ---- fp32 section ----
    float* fbase  = (float*)(us + 14548992);
    float* pre1   = fbase;                         // 131072 (reused as projout)
    float* delta  = fbase + 131072;                // 256
    float* coeff  = fbase + 131328;                // 13*256
    float* Bx     = fbase + 134656;                // 131072
    float* Tm     = fbase + 265728;                // 256*6144
    float* gates  = fbase + 1838592;               // 1572864
    float* projout = pre1;

    LnParams lpOff; lpOff.pre = nullptr; lpOff.g = nullptr; lpOff.beta = nullptr;
    lpOff.w2 = nullptr; lpOff.b2 = nullptr; lpOff.delta = nullptr; lpOff.coeff = nullptr;
    lpOff.lnd_y = -1;

    // ---- 1. unified prep (14 segments + A^T) ----
    PrepArgs pa;
    int sidx = 0;
    auto LIN = [&](const float* s, unsigned short* d, int n4) {
        pa.sA[sidx]=s; pa.sB[sidx]=s; pa.dst[sidx]=d; pa.n4[sidx]=n4;
        pa.dRL4[sidx]=n4; pa.sRLA4[sidx]=0; pa.sRLB4[sidx]=0;
        pa.half4[sidx]=n4; pa.offA[sidx]=0; ++sidx;
    };
    LIN(h_prev, hpb,     32768);
    LIN(A,      Pw,      65536);
    LIN(dn_w1,  dn_w1b,  65536);
    LIN(Bm,     Bmb,     65536);
    LIN(ain_w,  ain_wb,  196608);
    LIN(aout_w, aout_wb, 65536);
    pa.sA[sidx]=proj_w; pa.sB[sidx]=proj_w + 1024; pa.dst[sidx]=proj_wb; pa.n4[sidx]=262144;
    pa.dRL4[sidx]=512; pa.sRLA4[sidx]=640; pa.sRLB4[sidx]=640; pa.half4[sidx]=128; pa.offA[sidx]=0; ++sidx;
    pa.sA[sidx]=proj_w; pa.sB[sidx]=proj_w; pa.dst[sidx]=P2b; pa.n4[sidx]=65536;
    pa.dRL4[sidx]=128; pa.sRLA4[sidx]=640; pa.sRLB4[sidx]=640; pa.half4[sidx]=128; pa.offA[sidx]=128; ++sidx;
    for (int s = 0; s < 3; ++s) {
        pa.sA[sidx]=wih + (size_t)s*1048576; pa.sB[sidx]=whh + (size_t)s*1048576;
        pa.dst[sidx]=Wcat + (size_t)s*2097152; pa.n4[sidx]=524288;
        pa.dRL4[sidx]=256; pa.sRLA4[sidx]=128; pa.sRLB4[sidx]=128; pa.half4[sidx]=128; pa.offA[sidx]=0; ++sidx;
    }
    for (int s = 0; s < 3; ++s) {
        pa.sA[sidx]=x; pa.sB[sidx]=lstm_h + (size_t)s*131072;
        pa.dst[sidx]=Xcat + (size_t)s*262144; pa.n4[sidx]=65536;
        pa.dRL4[sidx]=256; pa.sRLA4[sidx]=128; pa.sRLB4[sidx]=128; pa.half4[sidx]=128; pa.offA[sidx]=0; ++sidx;
    }
    pa.A = A; pa.ATb = ATb;
    prep_kernel<<<2304, 256, 0, stream>>>(pa);

    GemmArgs ga;
    // ---- 2. batch1: dense1, Bx, G1 (A^2 + Q2), LSTM x3 ----
    ga.d[0] = { Xcat, dn_w1b, dn_b1, pre1, nullptr, nullptr, 256, 512, 512, 1024, 512, 512, 0, 0 };
    ga.d[1] = { Xcat, Bmb,    nullptr, Bx,  nullptr, nullptr, 256, 512, 512, 1024, 512, 512, 0, 0 };
    ga.d[2] = { Pw, ATb, nullptr, nullptr, Pw + 1*262144, Qa, 512, 512, 512, 512, 512, 512, 0, 0 };
    for (int s = 0; s < 3; ++s)
        ga.d[3 + s] = { Xcat + (size_t)s * 262144, Wcat + (size_t)s * 2097152, nullptr,
                        gates + (size_t)s * 524288, nullptr, nullptr, 256, 2048, 1024, 1024, 1024, 2048, 0, 0 };
    gemm_mfma<<<dim3(128, 6), 256, 0, stream>>>(ga, lpOff);

    // ---- 3. G2 [A^3,A^4]+Q4  +  fused LN/GELU/delta (y==1) ----
    LnParams lp1 = { pre1, dn_g, dn_beta, dn_w2, dn_b2, delta, coeff, 1 };
    ga.d[0] = { Pw, Qa, nullptr, nullptr, Pw + 2*262144, Qb, 1024, 512, 512, 512, 512, 512, 512, 0 };
    gemm_mfma<<<dim3(256, 2), 256, 0, stream>>>(ga, lp1);

    // ---- 4. G3 [A^5..A^8] (no dual-write needed) ----
    ga.d[0] = { Pw, Qb, nullptr, nullptr, Pw + 4*262144, nullptr, 2048, 512, 512, 512, 512, 512, 0, 0 };
    gemm_mfma<<<dim3(256, 1), 256, 0, stream>>>(ga, lpOff);

    // ---- 5. Taylor1 (k=1..8, N=4096) + U8 = bf16(A^8 h) ----
    ga.d[0] = { hpb, Pw, nullptr, Tm, nullptr, nullptr, 256, 4096, 512, 512, 512, 6144, 0, 0 };
    ga.d[1] = { hpb, Pw + 7*262144, nullptr, nullptr, U8b, nullptr, 256, 512, 512, 512, 512, 512, 0, 0 };
    gemm_mfma<<<dim3(256, 2), 256, 0, stream>>>(ga, lpOff);

    // ---- 6. Taylor2: T[k=9..12] = (A^j)(A^8 h), j=1..4 ----
    ga.d[0] = { U8b, Pw, nullptr, Tm + 4096, nullptr, nullptr, 256, 2048, 512, 512, 512, 6144, 0, 0 };
    gemm_mfma<<<dim3(128, 1), 256, 0, stream>>>(ga, lpOff);

    // ---- 7. fused pointwise (taylor accum + lstm cell) ----
    pointwise_fused<<<512, 256, 0, stream>>>(Tm, coeff, h_prev, delta, Bx, hssm, combb,
                                             gates, bih, bhh, lstm_c, decays, hnew, cnew);

    // ---- 8. q + kv x3 + projA (K=2048 over [hssm|h_new]) ----
    ga.d[0] = { combb, ain_wb, ain_b, nullptr, qb, nullptr, 256, 512, 512, 2048, 512, 512, 0, 0 };
    for (int s = 0; s < 3; ++s)
        ga.d[1 + s] = { combb + 512 + (size_t)s * 512, ain_wb + 262144, ain_b + 512,
                        nullptr, kvb + (size_t)s * 262144, nullptr, 256, 1024, 512, 2048, 512, 1024, 0, 0 };
    ga.d[4] = { combb, proj_wb, proj_b, projout, nullptr, nullptr, 256, 512, 2048, 2048, 2048, 512, 0, 0 };
    gemm_mfma<<<dim3(64, 5), 256, 0, stream>>>(ga, lpOff);

    // ---- 9. fused tail: attn + out-proj + proj-slice + final LN ----
    tail_kernel<<<256, 256, 0, stream>>>(qb, kvb, aout_wb, aout_b, P2b, projout,
                                         proj_g, proj_bt, out);
}

// Round 13
// 229.745 us; speedup vs baseline: 5.7586x; 1.0192x over previous
//
#include <hip/hip_runtime.h>
#include <math.h>

#define DIM 512
#define NB 256
#define KMAX 12   // Taylor terms (powers A^1..A^12)

using bf16x8 = __attribute__((ext_vector_type(8))) short;
using f32x4  = __attribute__((ext_vector_type(4))) float;
using float4v = __attribute__((ext_vector_type(4))) float;
using ushort4v = __attribute__((ext_vector_type(4))) unsigned short;

__device__ __forceinline__ unsigned short f2b(float f) {
    union { float f; unsigned int u; } v; v.f = f;
    unsigned int r = v.u + 0x7fffu + ((v.u >> 16) & 1u);
    return (unsigned short)(r >> 16);
}
__device__ __forceinline__ float b2f(unsigned short u) {
    union { unsigned int u; float f; } v; v.u = ((unsigned int)u) << 16;
    return v.f;
}
__device__ __forceinline__ ushort4v f2b4(float4v v) {
    ushort4v o;
    o.x = f2b(v.x); o.y = f2b(v.y); o.z = f2b(v.z); o.w = f2b(v.w);
    return o;
}

__device__ __forceinline__ void block_reduce2(float& s, float& q, float* sb1, float* sb2)
{
    int tid = threadIdx.x;
    #pragma unroll
    for (int off = 32; off > 0; off >>= 1) {
        s += __shfl_down(s, off);
        q += __shfl_down(q, off);
    }
    if ((tid & 63) == 0) { sb1[tid >> 6] = s; sb2[tid >> 6] = q; }
    __syncthreads();
    s = sb1[0] + sb1[1] + sb1[2] + sb1[3];
    q = sb2[0] + sb2[1] + sb2[2] + sb2[3];
    __syncthreads();
}

// ---------------------------------------------------------------------------
// Batched bf16 MFMA GEMM, BK=128.  C[m,n]=sum_k X[m,k]W[n,k]+b.
// acc: 0=store, 1=Cf+=, 2=atomicAdd(Cf).  Ct: transposed dual-write.
// lp.lnd_y == blockIdx.y -> fused LN/GELU/delta branch.  K % 128 == 0.
// ---------------------------------------------------------------------------
struct GemmDesc {
    const unsigned short* X;
    const unsigned short* W;
    const float* bias;
    float* Cf;
    unsigned short* Cb;
    unsigned short* Ct;
    int M, N, K, ldX, ldW, ldC, tr_row0, acc;
};
struct GemmArgs { GemmDesc d[10]; };
struct LnParams {
    const float* pre; const float* g; const float* beta;
    const float* w2; const float* b2; float* delta; float* coeff;
    int lnd_y;
};

__global__ __launch_bounds__(256) void gemm_mfma(GemmArgs args, LnParams lp)
{
    __shared__ unsigned short lsA[2][8192];
    __shared__ unsigned short lsB[2][8192];
    __shared__ float sb1[4], sb2[4];

    if ((int)blockIdx.y == lp.lnd_y) {
        int b = blockIdx.x, tid = threadIdx.x;
        int i0 = tid, i1 = tid + 256;
        float x0 = lp.pre[(size_t)b * DIM + i0];
        float x1 = lp.pre[(size_t)b * DIM + i1];
        float s = x0 + x1, q = x0 * x0 + x1 * x1;
        block_reduce2(s, q, sb1, sb2);
        float mean = s * (1.f / DIM);
        float var  = q * (1.f / DIM) - mean * mean;
        float inv  = rsqrtf(var + 1e-5f);
        float y0 = (x0 - mean) * inv * lp.g[i0] + lp.beta[i0];
        float y1 = (x1 - mean) * inv * lp.g[i1] + lp.beta[i1];
        float h0 = 0.5f * y0 * (1.f + erff(y0 * 0.70710678118654752f));
        float h1 = 0.5f * y1 * (1.f + erff(y1 * 0.70710678118654752f));
        float p = h0 * lp.w2[i0] + h1 * lp.w2[i1];
        float dummy = 0.f;
        block_reduce2(p, dummy, sb1, sb2);
        if (tid == 0) {
            float z = p + lp.b2[0];
            float d = (z > 20.f) ? z : log1pf(expf(z));
            lp.delta[b] = d;
            float c = 1.f;
            lp.coeff[b] = 1.f;
            for (int k = 1; k <= KMAX; ++k) { c *= d / (float)k; lp.coeff[k * 256 + b] = c; }
        }
        return;
    }

    GemmDesc de = args.d[blockIdx.y];
    int tn = de.N >> 6;
    int tiles = (de.M >> 6) * tn;
    int t = blockIdx.x;
    if (t >= tiles) return;
    int m0 = (t / tn) << 6;
    int n0 = (t % tn) << 6;

    int tid = threadIdx.x;
    int w = tid >> 6;
    int l = tid & 63;
    int nkt = de.K >> 7;      // BK=128

    int srow = w * 16 + (l >> 2);
    int schk = l & 3;
    const unsigned short* gA = de.X + (size_t)(m0 + srow) * de.ldX + schk * 8;
    const unsigned short* gB = de.W + (size_t)(n0 + srow) * de.ldW + schk * 8;
    unsigned short* lA = &lsA[0][(w * 64 + l) * 8];
    unsigned short* lB = &lsB[0][(w * 64 + l) * 8];

#define STAGE(bufi, kt)                                                          \
    do {                                                                         \
        for (int hh = 0; hh < 4; ++hh) {                                         \
            __builtin_amdgcn_global_load_lds(                                    \
                (const __attribute__((address_space(1))) unsigned int*)(gA + (size_t)(kt) * 128 + hh * 32), \
                (__attribute__((address_space(3))) unsigned int*)(lA + (bufi) * 8192 + hh * 2048), 16, 0, 0); \
            __builtin_amdgcn_global_load_lds(                                    \
                (const __attribute__((address_space(1))) unsigned int*)(gB + (size_t)(kt) * 128 + hh * 32), \
                (__attribute__((address_space(3))) unsigned int*)(lB + (bufi) * 8192 + hh * 2048), 16, 0, 0); \
        }                                                                        \
    } while (0)

    int mbase = (w >> 1) * 32;
    int nbase = (w & 1) * 32;

    f32x4 acc[2][2];
    #pragma unroll
    for (int i = 0; i < 2; ++i)
        #pragma unroll
        for (int j = 0; j < 2; ++j)
            acc[i][j] = (f32x4){0.f, 0.f, 0.f, 0.f};

    int kg = l >> 4;
    int fr = l & 15;
    int aslot = (mbase * 4 + fr * 4 + kg) * 8;
    int bslot = (nbase * 4 + fr * 4 + kg) * 8;

    STAGE(0, 0);

    for (int kt = 0; kt < nkt; ++kt) {
        __syncthreads();
        if (kt + 1 < nkt) STAGE((kt + 1) & 1, kt + 1);

        const unsigned short* bufA = &lsA[kt & 1][0];
        const unsigned short* bufB = &lsB[kt & 1][0];
        #pragma unroll
        for (int h = 0; h < 4; ++h) {
            bf16x8 a0 = *(const bf16x8*)(bufA + h * 2048 + aslot);
            bf16x8 a1 = *(const bf16x8*)(bufA + h * 2048 + aslot + 512);
            bf16x8 b0 = *(const bf16x8*)(bufB + h * 2048 + bslot);
            bf16x8 b1 = *(const bf16x8*)(bufB + h * 2048 + bslot + 512);
            acc[0][0] = __builtin_amdgcn_mfma_f32_16x16x32_bf16(a0, b0, acc[0][0], 0, 0, 0);
            acc[0][1] = __builtin_amdgcn_mfma_f32_16x16x32_bf16(a0, b1, acc[0][1], 0, 0, 0);
            acc[1][0] = __builtin_amdgcn_mfma_f32_16x16x32_bf16(a1, b0, acc[1][0], 0, 0, 0);
            acc[1][1] = __builtin_amdgcn_mfma_f32_16x16x32_bf16(a1, b1, acc[1][1], 0, 0, 0);
        }
    }

    #pragma unroll
    for (int mi = 0; mi < 2; ++mi) {
        #pragma unroll
        for (int ni = 0; ni < 2; ++ni) {
            int col = n0 + nbase + ni * 16 + fr;
            float bv = de.bias ? de.bias[col] : 0.f;
            #pragma unroll
            for (int r = 0; r < 4; ++r) {
                int row = m0 + mbase + mi * 16 + (l >> 4) * 4 + r;
                float v = acc[mi][ni][r] + bv;
                if (de.Cf) {
                    if (de.acc == 2)      atomicAdd(&de.Cf[(size_t)row * de.ldC + col], v);
                    else if (de.acc == 1) de.Cf[(size_t)row * de.ldC + col] += v;
                    else                  de.Cf[(size_t)row * de.ldC + col] = v;
                } else {
                    de.Cb[(size_t)row * de.ldC + col] = f2b(v);
                }
                if (de.Ct && row >= de.tr_row0)
                    de.Ct[(size_t)col * 512 + (row - de.tr_row0)] = f2b(v);
            }
        }
    }
#undef STAGE
}

// ---------------------------------------------------------------------------
// Unified prep: 14 convert segments + A^T transpose + gates zero-init.
// Grid 2432 x 256.
// ---------------------------------------------------------------------------
#define NSEG 14
struct PrepArgs {
    const float* sA[NSEG]; const float* sB[NSEG]; unsigned short* dst[NSEG];
    int n4[NSEG], dRL4[NSEG], sRLA4[NSEG], sRLB4[NSEG], half4[NSEG], offA[NSEG];
    const float* A; unsigned short* ATb;
    float* gates_zero; int gz_n4;
};
__global__ __launch_bounds__(256) void prep_kernel(PrepArgs a)
{
    __shared__ float tile[32][33];
    int bid = blockIdx.x, tid = threadIdx.x;
    if (bid < 2048) {
        const int gstride = 2048 * 256;
        int g0 = bid * 256 + tid;
        for (int seg = 0; seg < NSEG; ++seg) {
            int n4 = a.n4[seg];
            const float* sA = a.sA[seg];
            const float* sB = a.sB[seg];
            unsigned short* d = a.dst[seg];
            int dRL4 = a.dRL4[seg], sRLA4 = a.sRLA4[seg], sRLB4 = a.sRLB4[seg];
            int half4 = a.half4[seg], offA = a.offA[seg];
            for (int i = g0; i < n4; i += gstride) {
                int r = i / dRL4, c = i - r * dRL4;
                const float* src = (c < half4)
                    ? sA + ((size_t)r * sRLA4 + offA + c) * 4
                    : sB + ((size_t)r * sRLB4 + (c - half4)) * 4;
                float4v v = *(const float4v*)src;
                *(ushort4v*)(d + (size_t)i * 4) = f2b4(v);
            }
        }
    } else if (bid < 2304) {
        int tt = bid - 2048;
        int bx = tt & 15, by = tt >> 4;
        int tx = tid & 31, ty = tid >> 5;
        #pragma unroll
        for (int i = 0; i < 32; i += 8)
            tile[ty + i][tx] = a.A[(size_t)(by * 32 + ty + i) * 512 + bx * 32 + tx];
        __syncthreads();
        #pragma unroll
        for (int i = 0; i < 32; i += 8)
            a.ATb[(size_t)(bx * 32 + ty + i) * 512 + by * 32 + tx] = f2b(tile[tx][ty + i]);
    } else {
        // zero gates (for split-K atomic accumulation)
        float4v* gz = (float4v*)a.gates_zero;
        int g0 = (bid - 2304) * 256 + tid;
        const int gstride = 128 * 256;
        float4v z = (float4v){0.f, 0.f, 0.f, 0.f};
        for (int i = g0; i < a.gz_n4; i += gstride) gz[i] = z;
    }
}

// ---------------------------------------------------------------------------
// Fused pointwise: Taylor accum (K=12) + LSTM cell + projout bias-seed.
// combb (256 x 2048): [hssm | h_new s=0..2]
// Grid 640 x 256 (f4 work: 32768 taylor + 98304 lstm + 32768 projseed).
// ---------------------------------------------------------------------------
__global__ void pointwise_fused(
    const float* __restrict__ Tm, const float* __restrict__ coeff,
    const float* __restrict__ h_prev, const float* __restrict__ delta,
    const float* __restrict__ Bx, float* __restrict__ hssm,
    unsigned short* __restrict__ combb,
    const float* __restrict__ gates, const float* __restrict__ bih,
    const float* __restrict__ bhh, const float* __restrict__ cin,
    const float* __restrict__ decays,
    float* __restrict__ hout, float* __restrict__ cout,
    const float* __restrict__ proj_b, float* __restrict__ projout)
{
    int idx4 = blockIdx.x * 256 + threadIdx.x;
    int base = idx4 * 4;
    if (base < 131072) {
        int b = base >> 9, i = base & 511;
        const float* Tr = Tm + (size_t)b * (KMAX * DIM) + i;
        float4v a = *(const float4v*)(h_prev + base);
        #pragma unroll
        for (int k = 1; k <= KMAX; ++k) {
            float c = coeff[k * 256 + b];
            float4v t = *(const float4v*)(Tr + (size_t)(k - 1) * DIM);
            a.x += c * t.x; a.y += c * t.y; a.z += c * t.z; a.w += c * t.w;
        }
        float dl = delta[b];
        float4v bx = *(const float4v*)(Bx + base);
        a.x += dl * bx.x; a.y += dl * bx.y; a.z += dl * bx.z; a.w += dl * bx.w;
        *(float4v*)(hssm + base) = a;
        *(ushort4v*)(combb + (size_t)b * 2048 + i) = f2b4(a);
    } else if (base < 524288) {
        int i2 = base - 131072;
        int s = i2 / (NB * DIM);
        int r = i2 - s * (NB * DIM);
        int b = r >> 9, d = r & 511;
        const float* gr = gates + (size_t)s * 524288 + (size_t)b * 2048 + d;
        const float* bi = bih + s * 2048 + d;
        const float* bh = bhh + s * 2048 + d;
        float4v gi = *(const float4v*)(gr);
        float4v gf = *(const float4v*)(gr + 512);
        float4v gg = *(const float4v*)(gr + 1024);
        float4v go = *(const float4v*)(gr + 1536);
        float4v bi0 = *(const float4v*)(bi),        bh0 = *(const float4v*)(bh);
        float4v bi1 = *(const float4v*)(bi + 512),  bh1 = *(const float4v*)(bh + 512);
        float4v bi2 = *(const float4v*)(bi + 1024), bh2 = *(const float4v*)(bh + 1024);
        float4v bi3 = *(const float4v*)(bi + 1536), bh3 = *(const float4v*)(bh + 1536);
        float4v c = *(const float4v*)(cin + i2);
        float dec = decays[s];
        float4v hn, cn;
        #pragma unroll
        for (int j = 0; j < 4; ++j) {
            float vgi = ((const float*)&gi)[j] + ((const float*)&bi0)[j] + ((const float*)&bh0)[j];
            float vgf = ((const float*)&gf)[j] + ((const float*)&bi1)[j] + ((const float*)&bh1)[j];
            float vgg = ((const float*)&gg)[j] + ((const float*)&bi2)[j] + ((const float*)&bh2)[j];
            float vgo = ((const float*)&go)[j] + ((const float*)&bi3)[j] + ((const float*)&bh3)[j];
            float ig = 1.f / (1.f + expf(-vgi));
            float fg = 1.f / (1.f + expf(-vgf));
            float g_ = tanhf(vgg);
            float og = 1.f / (1.f + expf(-vgo));
            float cc = ((const float*)&c)[j];
            float craw = fg * cc + ig * g_;
            ((float*)&hn)[j] = og * tanhf(craw);
            ((float*)&cn)[j] = dec * cc + (1.f - dec) * craw;
        }
        *(float4v*)(hout + i2) = hn;
        *(float4v*)(cout + i2) = cn;
        *(ushort4v*)(combb + (size_t)b * 2048 + 512 + s * 512 + d) = f2b4(hn);
    } else {
        // seed projout[b, :] = proj_b[:]  (split-K projA atomically accumulates)
        int i = idx4 - 131072;          // 0..32767 f4 units
        int c4 = i & 127;
        float4v pb = *(const float4v*)(proj_b + c4 * 4);
        *(float4v*)(projout + (size_t)i * 4) = pb;
    }
}

// ---------------------------------------------------------------------------
// Fused tail: attn softmax + fused = ctx.aout_w^T + aout_b
//           + out = LN(projA + fused.P2^T).  One block per row b.
// ---------------------------------------------------------------------------
__global__ __launch_bounds__(256) void tail_kernel(
    const unsigned short* __restrict__ qb, const unsigned short* __restrict__ kvb,
    const unsigned short* __restrict__ aout_wb, const float* __restrict__ aout_b,
    const unsigned short* __restrict__ P2b, const float* __restrict__ projA,
    const float* __restrict__ fin_g, const float* __restrict__ fin_beta,
    float* __restrict__ outp)
{
    __shared__ float ctxs[512];
    __shared__ float fusedl[512];
    __shared__ float totals[512];
    __shared__ float sb1[4], sb2[4];
    int b = blockIdx.x, tid = threadIdx.x;

    if (tid < 128) {
        int h = tid >> 4, sub = (tid & 15) * 4;
        int col = h * 64 + sub;
        ushort4v q4 = *(const ushort4v*)(qb + (size_t)b * 512 + col);
        float qf[4] = { b2f(q4.x), b2f(q4.y), b2f(q4.z), b2f(q4.w) };
        float p[3];
        ushort4v k4[3], v4[3];
        #pragma unroll
        for (int s = 0; s < 3; ++s) {
            k4[s] = *(const ushort4v*)(kvb + (size_t)s * 262144 + (size_t)b * 1024 + col);
            v4[s] = *(const ushort4v*)(kvb + (size_t)s * 262144 + (size_t)b * 1024 + 512 + col);
            p[s] = qf[0] * b2f(k4[s].x) + qf[1] * b2f(k4[s].y)
                 + qf[2] * b2f(k4[s].z) + qf[3] * b2f(k4[s].w);
        }
        #pragma unroll
        for (int off = 1; off < 16; off <<= 1) {
            p[0] += __shfl_xor(p[0], off);
            p[1] += __shfl_xor(p[1], off);
            p[2] += __shfl_xor(p[2], off);
        }
        const float scale = 0.125f;
        float p0 = p[0] * scale, p1 = p[1] * scale, p2 = p[2] * scale;
        float m = fmaxf(p0, fmaxf(p1, p2));
        float w0 = expf(p0 - m), w1 = expf(p1 - m), w2 = expf(p2 - m);
        float invs = 1.f / (w0 + w1 + w2);
        ctxs[col + 0] = (w0 * b2f(v4[0].x) + w1 * b2f(v4[1].x) + w2 * b2f(v4[2].x)) * invs;
        ctxs[col + 1] = (w0 * b2f(v4[0].y) + w1 * b2f(v4[1].y) + w2 * b2f(v4[2].y)) * invs;
        ctxs[col + 2] = (w0 * b2f(v4[0].z) + w1 * b2f(v4[1].z) + w2 * b2f(v4[2].z)) * invs;
        ctxs[col + 3] = (w0 * b2f(v4[0].w) + w1 * b2f(v4[1].w) + w2 * b2f(v4[2].w)) * invs;
    }
    __syncthreads();

    for (int jj = tid; jj < 512; jj += 256) {
        float acc = aout_b[jj];
        const unsigned short* wr = aout_wb + (size_t)jj * 512;
        for (int k = 0; k < 512; k += 8) {
            ushort4v w0 = *(const ushort4v*)(wr + k);
            ushort4v w1 = *(const ushort4v*)(wr + k + 4);
            acc += ctxs[k+0]*b2f(w0.x) + ctxs[k+1]*b2f(w0.y)
                 + ctxs[k+2]*b2f(w0.z) + ctxs[k+3]*b2f(w0.w)
                 + ctxs[k+4]*b2f(w1.x) + ctxs[k+5]*b2f(w1.y)
                 + ctxs[k+6]*b2f(w1.z) + ctxs[k+7]*b2f(w1.w);
        }
        fusedl[jj] = acc;
    }
    __syncthreads();

    for (int ii = tid; ii < 512; ii += 256) {
        float acc = projA[(size_t)b * 512 + ii];
        const unsigned short* pr = P2b + (size_t)ii * 512;
        for (int j = 0; j < 512; j += 8) {
            ushort4v w0 = *(const ushort4v*)(pr + j);
            ushort4v w1 = *(const ushort4v*)(pr + j + 4);
            acc += fusedl[j+0]*b2f(w0.x) + fusedl[j+1]*b2f(w0.y)
                 + fusedl[j+2]*b2f(w0.z) + fusedl[j+3]*b2f(w0.w)
                 + fusedl[j+4]*b2f(w1.x) + fusedl[j+5]*b2f(w1.y)
                 + fusedl[j+6]*b2f(w1.z) + fusedl[j+7]*b2f(w1.w);
        }
        totals[ii] = acc;
    }
    __syncthreads();

    float x0 = totals[tid], x1 = totals[tid + 256];
    float s = x0 + x1, q = x0 * x0 + x1 * x1;
    block_reduce2(s, q, sb1, sb2);
    float mean = s * (1.f / DIM);
    float var  = q * (1.f / DIM) - mean * mean;
    float inv  = rsqrtf(var + 1e-5f);
    outp[(size_t)b * DIM + tid]       = (x0 - mean) * inv * fin_g[tid]       + fin_beta[tid];
    outp[(size_t)b * DIM + tid + 256] = (x1 - mean) * inv * fin_g[tid + 256] + fin_beta[tid + 256];
}

// ---------------------------------------------------------------------------
extern "C" void kernel_launch(void* const* d_in, const int* in_sizes, int n_in,
                              void* d_out, int out_size, void* d_ws, size_t ws_size,
                              hipStream_t stream)
{
    const float* x        = (const float*)d_in[0];
    const float* h_prev   = (const float*)d_in[1];
    const float* lstm_h   = (const float*)d_in[2];
    const float* lstm_c   = (const float*)d_in[3];
    const float* A        = (const float*)d_in[4];
    const float* Bm       = (const float*)d_in[5];
    const float* dn_w1    = (const float*)d_in[6];
    const float* dn_b1    = (const float*)d_in[7];
    const float* dn_g     = (const float*)d_in[8];
    const float* dn_beta  = (const float*)d_in[9];
    const float* dn_w2    = (const float*)d_in[10];
    const float* dn_b2    = (const float*)d_in[11];
    const float* wih      = (const float*)d_in[12];
    const float* whh      = (const float*)d_in[13];
    const float* bih      = (const float*)d_in[14];
    const float* bhh      = (const float*)d_in[15];
    const float* decays   = (const float*)d_in[16];
    const float* ain_w    = (const float*)d_in[17];
    const float* ain_b    = (const float*)d_in[18];
    const float* aout_w   = (const float*)d_in[19];
    const float* aout_b   = (const float*)d_in[20];
    const float* proj_w   = (const float*)d_in[21];
    const float* proj_b   = (const float*)d_in[22];
    const float* proj_g   = (const float*)d_in[23];
    const float* proj_bt  = (const float*)d_in[24];

    float* out  = (float*)d_out;
    float* hssm = out + 131072;
    float* hnew = out + 262144;
    float* cnew = out + 655360;

    // ---- workspace (bf16 section) ----
    unsigned short* us = (unsigned short*)d_ws;
    unsigned short* hpb     = us;                  // 131072
    unsigned short* ATb     = us + 131072;         // 262144
    unsigned short* dn_w1b  = us + 393216;         // 262144
    unsigned short* Bmb     = us + 655360;         // 262144
    unsigned short* ain_wb  = us + 917504;         // 786432
    unsigned short* proj_wb = us + 1703936;        // 1048576 (512x2048 packed [P0|P1])
    unsigned short* P2b     = us + 2752512;        // 262144
    unsigned short* aout_wb = us + 3014656;        // 262144
    unsigned short* Pw      = us + 3276800;        // 8*262144 [A^1..A^8]
    unsigned short* Qa      = us + 5373952;        // 262144
    unsigned short* Qb      = us + 5636096;        // 262144
    unsigned short* Wcat    = us + 5898240;        // 6291456
    unsigned short* Xcat    = us + 12189696;       // 786432
    unsigned short* combb   = us + 12976128;       // 524288 (256x2048) [hssm|hnew*3]
    unsigned short* qb      = us + 13500416;       // 131072
    unsigned short* kvb     = us + 13631488;       // 786432
    unsigned short* U8b     = us + 14417920;       // 131072 (bf16 A^8 h)
    // ---- fp32 section ----
    float* fbase  = (float*)(us + 14548992);
    float* pre1   = fbase;                         // 131072 (reused as projout)
    float* delta  = fbase + 131072;                // 256
    float* coeff  = fbase + 131328;                // 13*256
    float* Bx     = fbase + 134656;                // 131072
    float* Tm     = fbase + 265728;                // 256*6144
    float* gates  = fbase + 1838592;               // 1572864
    float* projout = pre1;

    LnParams lpOff; lpOff.pre = nullptr; lpOff.g = nullptr; lpOff.beta = nullptr;
    lpOff.w2 = nullptr; lpOff.b2 = nullptr; lpOff.delta = nullptr; lpOff.coeff = nullptr;
    lpOff.lnd_y = -1;

    // ---- 1. unified prep (14 segments + A^T + gates zero) ----
    PrepArgs pa;
    int sidx = 0;
    auto LIN = [&](const float* s, unsigned short* d, int n4) {
        pa.sA[sidx]=s; pa.sB[sidx]=s; pa.dst[sidx]=d; pa.n4[sidx]=n4;
        pa.dRL4[sidx]=n4; pa.sRLA4[sidx]=0; pa.sRLB4[sidx]=0;
        pa.half4[sidx]=n4; pa.offA[sidx]=0; ++sidx;
    };
    LIN(h_prev, hpb,     32768);
    LIN(A,      Pw,      65536);
    LIN(dn_w1,  dn_w1b,  65536);
    LIN(Bm,     Bmb,     65536);
    LIN(ain_w,  ain_wb,  196608);
    LIN(aout_w, aout_wb, 65536);
    pa.sA[sidx]=proj_w; pa.sB[sidx]=proj_w + 1024; pa.dst[sidx]=proj_wb; pa.n4[sidx]=262144;
    pa.dRL4[sidx]=512; pa.sRLA4[sidx]=640; pa.sRLB4[sidx]=640; pa.half4[sidx]=128; pa.offA[sidx]=0; ++sidx;
    pa.sA[sidx]=proj_w; pa.sB[sidx]=proj_w; pa.dst[sidx]=P2b; pa.n4[sidx]=65536;
    pa.dRL4[sidx]=128; pa.sRLA4[sidx]=640; pa.sRLB4[sidx]=640; pa.half4[sidx]=128; pa.offA[sidx]=128; ++sidx;
    for (int s = 0; s < 3; ++s) {
        pa.sA[sidx]=wih + (size_t)s*1048576; pa.sB[sidx]=whh + (size_t)s*1048576;
        pa.dst[sidx]=Wcat + (size_t)s*2097152; pa.n4[sidx]=524288;
        pa.dRL4[sidx]=256; pa.sRLA4[sidx]=128; pa.sRLB4[sidx]=128; pa.half4[sidx]=128; pa.offA[sidx]=0; ++sidx;
    }
    for (int s = 0; s < 3; ++s) {
        pa.sA[sidx]=x; pa.sB[sidx]=lstm_h + (size_t)s*131072;
        pa.dst[sidx]=Xcat + (size_t)s*262144; pa.n4[sidx]=65536;
        pa.dRL4[sidx]=256; pa.sRLA4[sidx]=128; pa.sRLB4[sidx]=128; pa.half4[sidx]=128; pa.offA[sidx]=0; ++sidx;
    }
    pa.A = A; pa.ATb = ATb;
    pa.gates_zero = gates; pa.gz_n4 = 393216;
    prep_kernel<<<2432, 256, 0, stream>>>(pa);

    GemmArgs ga;
    // ---- 2. batch1: dense1, Bx, G1 (A^2 + Q2), LSTM x3 split-K x2 (atomic) ----
    ga.d[0] = { Xcat, dn_w1b, dn_b1, pre1, nullptr, nullptr, 256, 512, 512, 1024, 512, 512, 0, 0 };
    ga.d[1] = { Xcat, Bmb,    nullptr, Bx,  nullptr, nullptr, 256, 512, 512, 1024, 512, 512, 0, 0 };
    ga.d[2] = { Pw, ATb, nullptr, nullptr, Pw + 1*262144, Qa, 512, 512, 512, 512, 512, 512, 0, 0 };
    for (int s = 0; s < 3; ++s)
        for (int half = 0; half < 2; ++half)
            ga.d[3 + s * 2 + half] = { Xcat + (size_t)s * 262144 + half * 512,
                                       Wcat + (size_t)s * 2097152 + half * 512, nullptr,
                                       gates + (size_t)s * 524288, nullptr, nullptr,
                                       256, 2048, 512, 1024, 1024, 2048, 0, 2 };
    gemm_mfma<<<dim3(128, 9), 256, 0, stream>>>(ga, lpOff);

    // ---- 3. G2 [A^3,A^4]+Q4  +  fused LN/GELU/delta (y==1) ----
    LnParams lp1 = { pre1, dn_g, dn_beta, dn_w2, dn_b2, delta, coeff, 1 };
    ga.d[0] = { Pw, Qa, nullptr, nullptr, Pw + 2*262144, Qb, 1024, 512, 512, 512, 512, 512, 512, 0 };
    gemm_mfma<<<dim3(256, 2), 256, 0, stream>>>(ga, lp1);

    // ---- 4. G3 [A^5..A^8] ----
    ga.d[0] = { Pw, Qb, nullptr, nullptr, Pw + 4*262144, nullptr, 2048, 512, 512, 512, 512, 512, 0, 0 };
    gemm_mfma<<<dim3(256, 1), 256, 0, stream>>>(ga, lpOff);

    // ---- 5. Taylor1 (k=1..8, N=4096) + U8 = bf16(A^8 h) ----
    ga.d[0] = { hpb, Pw, nullptr, Tm, nullptr, nullptr, 256, 4096, 512, 512, 512, 6144, 0, 0 };
    ga.d[1] = { hpb, Pw + 7*262144, nullptr, nullptr, U8b, nullptr, 256, 512, 512, 512, 512, 512, 0, 0 };
    gemm_mfma<<<dim3(256, 2), 256, 0, stream>>>(ga, lpOff);

    // ---- 6. Taylor2: T[k=9..12] = (A^j)(A^8 h), j=1..4 ----
    ga.d[0] = { U8b, Pw, nullptr, Tm + 4096, nullptr, nullptr, 256, 2048, 512, 512, 512, 6144, 0, 0 };
    gemm_mfma<<<dim3(128, 1), 256, 0, stream>>>(ga, lpOff);

    // ---- 7. fused pointwise (taylor accum + lstm cell + projout seed) ----
    pointwise_fused<<<640, 256, 0, stream>>>(Tm, coeff, h_prev, delta, Bx, hssm, combb,
                                             gates, bih, bhh, lstm_c, decays, hnew, cnew,
                                             proj_b, projout);

    // ---- 8. q + kv x3 + projA split-K x4 (atomic into seeded projout) ----
    ga.d[0] = { combb, ain_wb, ain_b, nullptr, qb, nullptr, 256, 512, 512, 2048, 512, 512, 0, 0 };
    for (int s = 0; s < 3; ++s)
        ga.d[1 + s] = { combb + 512 + (size_t)s * 512, ain_wb + 262144, ain_b + 512,
                        nullptr, kvb + (size_t)s * 262144, nullptr, 256, 1024, 512, 2048, 512, 1024, 0, 0 };
    for (int ks = 0; ks < 4; ++ks)
        ga.d[4 + ks] = { combb + ks * 512, proj_wb + ks * 512, nullptr, projout, nullptr, nullptr,
                         256, 512, 512, 2048, 2048, 512, 0, 2 };
    gemm_mfma<<<dim3(64, 8), 256, 0, stream>>>(ga, lpOff);

    // ---- 9. fused tail: attn + out-proj + proj-slice + final LN ----
    tail_kernel<<<256, 256, 0, stream>>>(qb, kvb, aout_wb, aout_b, P2b, projout,
                                         proj_g, proj_bt, out);
}